// Round 3
// baseline (1292.362 us; speedup 1.0000x reference)
//
#include <hip/hip_runtime.h>
#include <hip/hip_cooperative_groups.h>
#include <hip/hip_bf16.h>
#include <math.h>

namespace cg = cooperative_groups;

typedef short short8_t __attribute__((ext_vector_type(8)));
typedef float floatx4  __attribute__((ext_vector_type(4)));
typedef float floatx2  __attribute__((ext_vector_type(2)));
typedef unsigned int uint;

#define EPB 1024   // edges per histogram/scatter block
#define BSH 9      // 512 nodes per coarse bucket

// ---------------- bf16 helpers (RNE) ----------------------------------------

__device__ inline unsigned short f2b(float f) {
    uint u = __float_as_uint(f);
    u += 0x7fff + ((u >> 16) & 1);
    return (unsigned short)(u >> 16);
}
__device__ inline uint pack2(float a, float b) {
    return (uint)f2b(a) | ((uint)f2b(b) << 16);
}

// ---------------- fp8 (e4m3) helpers -----------------------------------------

__device__ inline uint enc4_fp8(float f0, float f1, float f2, float f3) {
    uint v = __builtin_amdgcn_cvt_pk_fp8_f32(f0, f1, 0, false);
    v = __builtin_amdgcn_cvt_pk_fp8_f32(f2, f3, v, true);
    return v;
}
__device__ inline unsigned char enc1_fp8(float f) {
    return (unsigned char)(__builtin_amdgcn_cvt_pk_fp8_f32(f, f, 0, false) & 0xff);
}

// Lesson ledger:
//  R10/R13: GLOBAL atomic histogram pinned ~43-50us — replaced by LDS hist.
//  R12: co-scheduling light branches in one grid is free.
//  R11/R14/R15: a latency-bound phase inherits a fused kernel's worst-phase
//       occupancy — per-BLOCK fusion of gather into MFMA collapsed (139us).
//  R9: keep scatter targets packed (L2-resident).
//  R16: split structure, 9 dispatches -> 258us. Work models sum to ~120us;
//       residual ~135us / 9 ~= 15us fixed cost PER DISPATCH.
//  R17 (this round): cut dispatches 9 -> 4 without losing occupancy:
//       (a) cooperative grid-stride mega-kernel for preprocessing+gather1
//           (grid.sync between phases; every phase keeps native parallelism),
//       (b) head folded into linear2 epilogue (per-node Wout projection +
//           2-float atomics + last-block log_softmax).

// ---------------- shared device phase bodies ---------------------------------

__device__ inline void scan256(int* ss, int t) {
#pragma unroll
    for (int off = 1; off < 256; off <<= 1) {
        int u = (t >= off) ? ss[t - off] : 0;
        __syncthreads();
        ss[t] += u;
        __syncthreads();
    }
}

// phase A virtual block: hist | cvt_x | cvt_w | zero(plog,counter) | gstart
__device__ inline void phaseA_iter(
    int vb, int tid, int* h,
    const int* __restrict__ dst, int* __restrict__ bhist, int E,
    const float* __restrict__ x, unsigned short* __restrict__ xb,
    unsigned char* __restrict__ xf8, int nX,
    const float* __restrict__ Wl1, const float* __restrict__ Wr1,
    const float* __restrict__ Wl2, const float* __restrict__ Wr2,
    unsigned short* __restrict__ wbuf,
    float* __restrict__ plog, int* __restrict__ counter,
    const int* __restrict__ batch, int* __restrict__ gstart, int N, int G,
    int bHist, int bCvtX, int bCvtW) {
    if (vb < bHist) {
        h[tid] = 0;
        __syncthreads();
        int e = vb * EPB + tid * 4;
        if (e + 3 < E) {
            int4 d4 = *(const int4*)(dst + e);
            atomicAdd(&h[d4.x >> BSH], 1);
            atomicAdd(&h[d4.y >> BSH], 1);
            atomicAdd(&h[d4.z >> BSH], 1);
            atomicAdd(&h[d4.w >> BSH], 1);
        } else {
            for (int k = e; k < E; ++k) atomicAdd(&h[dst[k] >> BSH], 1);
        }
        __syncthreads();
        bhist[(size_t)vb * 256 + tid] = h[tid];
        __syncthreads();
    } else if (vb < bHist + bCvtX) {
        int i = ((vb - bHist) * 256 + tid) * 8;
        if (i < nX) {
            float4 v0 = *(const float4*)(x + i);
            float4 v1 = *(const float4*)(x + i + 4);
            uint4 ob;
            ob.x = pack2(v0.x, v0.y);
            ob.y = pack2(v0.z, v0.w);
            ob.z = pack2(v1.x, v1.y);
            ob.w = pack2(v1.z, v1.w);
            *(uint4*)(xb + i) = ob;
            uint2 of;
            of.x = enc4_fp8(v0.x, v0.y, v0.z, v0.w);
            of.y = enc4_fp8(v1.x, v1.y, v1.z, v1.w);
            *(uint2*)(xf8 + i) = of;
        }
    } else if (vb < bHist + bCvtX + bCvtW) {
        int i = (vb - bHist - bCvtX) * 256 + tid;
        if (i < 49152) {
            float v;
            if (i < 8192)       v = Wl1[i];
            else if (i < 16384) v = Wr1[i - 8192];
            else if (i < 32768) v = Wl2[i - 16384];
            else                v = Wr2[i - 32768];
            wbuf[i] = f2b(v);
        }
    } else if (vb == bHist + bCvtX + bCvtW) {
        for (int i = tid; i < 2 * G; i += 256) plog[i] = 0.f;
        if (tid == 0) *counter = 0;
    } else {
        for (int g = tid; g <= G; g += 256) {
            if (g == G) { gstart[G] = N; continue; }
            int lo = 0, hi = N;
            while (lo < hi) {
                int mid = (lo + hi) >> 1;
                if (batch[mid] < g) lo = mid + 1; else hi = mid;
            }
            gstart[g] = lo;
        }
    }
}

// column scan: for bucket k, exclusive-prefix bhist[:,k] over blocks; btot[k]=total
__device__ inline void scanbh_iter(int k, int t, int* ss,
                                   int* __restrict__ bhist,
                                   int* __restrict__ btot, int nb) {
    int b0 = t * 4;
    int v[4];
    int sum = 0;
#pragma unroll
    for (int i = 0; i < 4; ++i) {
        int b = b0 + i;
        v[i] = (b < nb) ? bhist[(size_t)b * 256 + k] : 0;
        sum += v[i];
    }
    ss[t] = sum;
    __syncthreads();
    scan256(ss, t);
    int run = ss[t] - sum;
#pragma unroll
    for (int i = 0; i < 4; ++i) {
        int b = b0 + i;
        if (b < nb) { bhist[(size_t)b * 256 + k] = run; run += v[i]; }
    }
    if (t == 0) btot[k] = ss[255];
    __syncthreads();   // protect ss before next virtual block
}

// scatter edges into bucket-grouped ebuf; record = (dst&511)<<23 | src
__device__ inline void scatter_iter(int b, int t, int* lbase, const int* bbS,
                                    const int* __restrict__ src,
                                    const int* __restrict__ dst,
                                    const int* __restrict__ bhist,
                                    int* __restrict__ ebuf, int E) {
    lbase[t] = bbS[t] + bhist[(size_t)b * 256 + t];
    __syncthreads();
    int e = b * EPB + t * 4;
    if (e + 3 < E) {
        int4 d4 = *(const int4*)(dst + e);
        int4 s4 = *(const int4*)(src + e);
        int k, p;
        k = d4.x >> BSH; p = atomicAdd(&lbase[k], 1); ebuf[p] = ((d4.x & 511) << 23) | s4.x;
        k = d4.y >> BSH; p = atomicAdd(&lbase[k], 1); ebuf[p] = ((d4.y & 511) << 23) | s4.y;
        k = d4.z >> BSH; p = atomicAdd(&lbase[k], 1); ebuf[p] = ((d4.z & 511) << 23) | s4.z;
        k = d4.w >> BSH; p = atomicAdd(&lbase[k], 1); ebuf[p] = ((d4.w & 511) << 23) | s4.w;
    } else {
        for (int q = e; q < E; ++q) {
            int d = dst[q];
            int p = atomicAdd(&lbase[d >> BSH], 1);
            ebuf[p] = ((d & 511) << 23) | src[q];
        }
    }
    __syncthreads();   // protect lbase before next virtual block
}

// per-bucket counting sort: 512-bin LDS histogram + scan -> row_start + csr_src
__device__ inline void bucket_iter(int k, int t, int* h2, int* ss, const int* bbS,
                                   const int* __restrict__ ebuf,
                                   int* __restrict__ row_start,
                                   int* __restrict__ csr_src, int N, int NB) {
    int s = bbS[k], e = bbS[k + 1];
    int node0 = k << BSH;
    int nn = N - node0; if (nn > 512) nn = 512;
    if (k == NB - 1 && t == 0) row_start[node0 + nn] = e;
    h2[t] = 0; h2[t + 256] = 0;
    __syncthreads();
    for (int i = s + t; i < e; i += 256)
        atomicAdd(&h2[((uint)ebuf[i]) >> 23], 1);
    __syncthreads();
    int a0 = h2[2 * t], a1 = h2[2 * t + 1];
    int ps = a0 + a1;
    ss[t] = ps;
    __syncthreads();
    scan256(ss, t);
    int base = ss[t] - ps;
    h2[2 * t] = base;
    h2[2 * t + 1] = base + a0;
    __syncthreads();
    int rs0 = h2[t];
    int rs1 = h2[t + 256];
    __syncthreads();
    if (t < nn)       row_start[node0 + t]       = s + rs0;
    if (t + 256 < nn) row_start[node0 + t + 256] = s + rs1;
    for (int i = s + t; i < e; i += 256) {
        int rec = ebuf[i];
        int j = ((uint)rec) >> 23;
        int pos = atomicAdd(&h2[j], 1);
        csr_src[s + pos] = rec & 0x7FFFFF;
    }
    __syncthreads();   // protect h2/ss before next virtual block
}

// ---------------- fp8 accumulate macro ---------------------------------------

#define ACCF8(v)                                                        \
    { floatx2 f = __builtin_amdgcn_cvt_pk_f32_fp8((v).x, false);        \
      a[0] += f[0]; a[1] += f[1];                                       \
      f = __builtin_amdgcn_cvt_pk_f32_fp8((v).x, true);                 \
      a[2] += f[0]; a[3] += f[1];                                       \
      f = __builtin_amdgcn_cvt_pk_f32_fp8((v).y, false);                \
      a[4] += f[0]; a[5] += f[1];                                       \
      f = __builtin_amdgcn_cvt_pk_f32_fp8((v).y, true);                 \
      a[6] += f[0]; a[7] += f[1]; }

// K=64 mean-gather for one virtual block (4 nodes, 1 node/wave, no LDS)
__device__ inline void gather1_iter(int vb, int tid,
                                    const unsigned char* __restrict__ xf8,
                                    const int* __restrict__ row_start,
                                    const int* __restrict__ csr_src,
                                    unsigned short* __restrict__ agg, int n_nodes) {
    int node = vb * 4 + (tid >> 6);
    if (node >= n_nodes) return;
    int lane = tid & 63;
    int grp = lane >> 3;
    int lp  = lane & 7;
    int s = row_start[node];
    int e = row_start[node + 1];
    float a[8];
#pragma unroll
    for (int q = 0; q < 8; ++q) a[q] = 0.f;
    int i = s + grp;
    for (; i + 8 < e; i += 16) {
        int u0 = csr_src[i];
        int u1 = csr_src[i + 8];
        uint2 v0 = *(const uint2*)(xf8 + (size_t)u0 * 64 + lp * 8);
        uint2 v1 = *(const uint2*)(xf8 + (size_t)u1 * 64 + lp * 8);
        ACCF8(v0);
        ACCF8(v1);
    }
    if (i < e) {
        int u0 = csr_src[i];
        uint2 v0 = *(const uint2*)(xf8 + (size_t)u0 * 64 + lp * 8);
        ACCF8(v0);
    }
#pragma unroll
    for (int q = 0; q < 8; ++q) {
        a[q] += __shfl_xor(a[q], 8);
        a[q] += __shfl_xor(a[q], 16);
        a[q] += __shfl_xor(a[q], 32);
    }
    if (grp == 0) {
        int d = e - s;
        float scale = (d > 0) ? (1.f / (float)d) : 1.f;
        uint4 o;
        o.x = pack2(a[0] * scale, a[1] * scale);
        o.y = pack2(a[2] * scale, a[3] * scale);
        o.z = pack2(a[4] * scale, a[5] * scale);
        o.w = pack2(a[6] * scale, a[7] * scale);
        *(uint4*)(agg + (size_t)node * 64 + lp * 8) = o;
    }
}

// ---------------- cooperative mega-kernel (preprocessing + gather1) ----------

struct MegaArgs {
    const int* src; const int* dst; int E;
    const float* x; unsigned short* xb; unsigned char* xf8; int nX;
    const float* Wl1; const float* Wr1; const float* Wl2; const float* Wr2;
    unsigned short* wbuf;
    float* plog; int* counter;
    const int* batch; int* gstart; int N; int G;
    int* bhist; int* btot; int* ebuf; int* row_start; int* csr_src;
    unsigned short* agg1;
    int bHist; int bCvtX; int bCvtW; int NB; int NV1;
};

__global__ __launch_bounds__(256, 8) void k_mega(MegaArgs A) {
    __shared__ int h[256];
    __shared__ int ss[256];
    __shared__ int bbS[257];
    __shared__ int lbase[256];
    __shared__ int h2[512];
    int tid = threadIdx.x;
    int nblk = (int)gridDim.x;
    cg::grid_group grid = cg::this_grid();

    // phase A: hist + cvt_x + cvt_w + zero + gstart
    int totalA = A.bHist + A.bCvtX + A.bCvtW + 2;
    for (int vb = blockIdx.x; vb < totalA; vb += nblk)
        phaseA_iter(vb, tid, h, A.dst, A.bhist, A.E, A.x, A.xb, A.xf8, A.nX,
                    A.Wl1, A.Wr1, A.Wl2, A.Wr2, A.wbuf, A.plog, A.counter,
                    A.batch, A.gstart, A.N, A.G, A.bHist, A.bCvtX, A.bCvtW);
    __threadfence();
    grid.sync();

    // scan_bh
    for (int k = blockIdx.x; k < 256; k += nblk)
        scanbh_iter(k, tid, ss, A.bhist, A.btot, A.bHist);
    __threadfence();
    grid.sync();

    // btot scan once (loop-invariant for scatter & bucket phases)
    {
        int v = A.btot[tid];
        ss[tid] = v;
        __syncthreads();
        scan256(ss, tid);
        bbS[tid] = ss[tid] - v;
        if (tid == 255) bbS[256] = ss[255];
        __syncthreads();
    }
    // scatter
    for (int b = blockIdx.x; b < A.bHist; b += nblk)
        scatter_iter(b, tid, lbase, bbS, A.src, A.dst, A.bhist, A.ebuf, A.E);
    __threadfence();
    grid.sync();

    // bucket counting sort
    for (int k = blockIdx.x; k < A.NB; k += nblk)
        bucket_iter(k, tid, h2, ss, bbS, A.ebuf, A.row_start, A.csr_src, A.N, A.NB);
    __threadfence();
    grid.sync();

    // gather1 (same wave-per-node shape as standalone: full latency hiding)
    for (int vb = blockIdx.x; vb < A.NV1; vb += nblk)
        gather1_iter(vb, tid, A.xf8, A.row_start, A.csr_src, A.agg1, A.N);
}

// ---------------- fallback standalone kernels (if coop launch unavailable) ---

__global__ __launch_bounds__(256) void k_phase_a_fb(
    const int* dst, int* bhist, int E,
    const float* x, unsigned short* xb, unsigned char* xf8, int nX,
    const float* Wl1, const float* Wr1, const float* Wl2, const float* Wr2,
    unsigned short* wbuf, float* plog, int* counter,
    const int* batch, int* gstart, int N, int G,
    int bHist, int bCvtX, int bCvtW) {
    __shared__ int h[256];
    phaseA_iter(blockIdx.x, threadIdx.x, h, dst, bhist, E, x, xb, xf8, nX,
                Wl1, Wr1, Wl2, Wr2, wbuf, plog, counter, batch, gstart, N, G,
                bHist, bCvtX, bCvtW);
}

__global__ __launch_bounds__(256) void k_scan_bh_fb(int* bhist, int* btot, int nb) {
    __shared__ int ss[256];
    scanbh_iter(blockIdx.x, threadIdx.x, ss, bhist, btot, nb);
}

__global__ __launch_bounds__(256) void k_scatter_fb(
    const int* src, const int* dst, const int* bhist, const int* btot,
    int* ebuf, int E) {
    __shared__ int ss[256];
    __shared__ int bbS[257];
    __shared__ int lbase[256];
    int t = threadIdx.x;
    int v = btot[t];
    ss[t] = v;
    __syncthreads();
    scan256(ss, t);
    bbS[t] = ss[t] - v;
    if (t == 255) bbS[256] = ss[255];
    __syncthreads();
    scatter_iter(blockIdx.x, t, lbase, bbS, src, dst, bhist, ebuf, E);
}

__global__ __launch_bounds__(256) void k_bucket_fb(
    const int* ebuf, const int* btot, int* row_start, int* csr_src, int N, int NB) {
    __shared__ int ss[256];
    __shared__ int bbS[257];
    __shared__ int h2[512];
    int t = threadIdx.x;
    int v = btot[t];
    ss[t] = v;
    __syncthreads();
    scan256(ss, t);
    bbS[t] = ss[t] - v;
    if (t == 255) bbS[256] = ss[255];
    __syncthreads();
    bucket_iter(blockIdx.x, t, h2, ss, bbS, ebuf, row_start, csr_src, N, NB);
}

__global__ void k_gather1_fb(const unsigned char* xf8, const int* row_start,
                             const int* csr_src, unsigned short* agg, int n_nodes) {
    gather1_iter(blockIdx.x, threadIdx.x, xf8, row_start, csr_src, agg, n_nodes);
}

// ---------------- gather layer 2 (K=128) -------------------------------------

__global__ void k_gather2(const unsigned char* __restrict__ h1f8,
                          const int* __restrict__ row_start,
                          const int* __restrict__ csr_src,
                          unsigned short* __restrict__ agg, int n_nodes) {
    int tid = threadIdx.x;
    int node = blockIdx.x * 4 + (tid >> 6);
    if (node >= n_nodes) return;
    int lane = tid & 63;
    int grp = lane >> 4;
    int lp  = lane & 15;
    int s = row_start[node];
    int e = row_start[node + 1];
    float a[8];
#pragma unroll
    for (int q = 0; q < 8; ++q) a[q] = 0.f;
    int i = s + grp;
    for (; i + 4 < e; i += 8) {
        int u0 = csr_src[i];
        int u1 = csr_src[i + 4];
        uint2 v0 = *(const uint2*)(h1f8 + (size_t)u0 * 128 + lp * 8);
        uint2 v1 = *(const uint2*)(h1f8 + (size_t)u1 * 128 + lp * 8);
        ACCF8(v0);
        ACCF8(v1);
    }
    if (i < e) {
        int u0 = csr_src[i];
        uint2 v0 = *(const uint2*)(h1f8 + (size_t)u0 * 128 + lp * 8);
        ACCF8(v0);
    }
#pragma unroll
    for (int q = 0; q < 8; ++q) {
        a[q] += __shfl_xor(a[q], 16);
        a[q] += __shfl_xor(a[q], 32);
    }
    if (grp == 0) {
        int d = e - s;
        float scale = (d > 0) ? (1.f / (float)d) : 1.f;
        uint4 o;
        o.x = pack2(a[0] * scale, a[1] * scale);
        o.y = pack2(a[2] * scale, a[3] * scale);
        o.z = pack2(a[4] * scale, a[5] * scale);
        o.w = pack2(a[6] * scale, a[7] * scale);
        *(uint4*)(agg + (size_t)node * 128 + lp * 8) = o;
    }
}

// ---------------- layer-1 MFMA linear: relu(agg@Wl.T + bl + x@Wr.T) ----------

__global__ __launch_bounds__(256) void k_linear1(
    const unsigned short* __restrict__ aggA, const unsigned short* __restrict__ xinA,
    const unsigned short* __restrict__ Wlb,  const float* __restrict__ bl,
    const unsigned short* __restrict__ Wrb,  unsigned short* __restrict__ out,
    unsigned char* __restrict__ outf8, int n_nodes) {
    constexpr int K = 64;
    constexpr int NCH = 4;
    __shared__ __align__(16) short As[128 * 32];   // 8 KB

    int tid  = threadIdx.x;
    int lane = tid & 63;
    int wave = tid >> 6;
    int quad = lane >> 4;
    int lr   = lane & 15;
    int node0 = blockIdx.x * 128;

    floatx4 acc[8][2];
#pragma unroll
    for (int mi = 0; mi < 8; ++mi)
#pragma unroll
        for (int ni = 0; ni < 2; ++ni)
            acc[mi][ni] = (floatx4){0.f, 0.f, 0.f, 0.f};

    int srow = tid >> 2;
    int sslot = tid & 3;

#pragma unroll
    for (int c = 0; c < NCH; ++c) {
        const unsigned short* srcA;
        const unsigned short* srcW;
        int kb;
        if (c < K / 32) { srcA = aggA; srcW = Wlb; kb = c * 32; }
        else            { srcA = xinA; srcW = Wrb; kb = c * 32 - K; }

        __syncthreads();
        {
            int n1 = node0 + srow;       if (n1 >= n_nodes) n1 = n_nodes - 1;
            int n2 = node0 + srow + 64;  if (n2 >= n_nodes) n2 = n_nodes - 1;
            uint4 v1 = *(const uint4*)(srcA + (size_t)n1 * K + kb + sslot * 8);
            uint4 v2 = *(const uint4*)(srcA + (size_t)n2 * K + kb + sslot * 8);
            *(uint4*)(&As[srow * 32 + sslot * 8]) = v1;
            *(uint4*)(&As[(srow + 64) * 32 + sslot * 8]) = v2;
        }
        __syncthreads();

        short8_t bfrag[2];
#pragma unroll
        for (int ni = 0; ni < 2; ++ni) {
            int j = wave * 32 + ni * 16 + lr;
            bfrag[ni] = *(const short8_t*)(srcW + (size_t)j * K + kb + quad * 8);
        }
#pragma unroll
        for (int mi = 0; mi < 8; ++mi) {
            short8_t af = *(const short8_t*)(&As[(mi * 16 + lr) * 32 + quad * 8]);
            acc[mi][0] = __builtin_amdgcn_mfma_f32_16x16x32_bf16(af, bfrag[0], acc[mi][0], 0, 0, 0);
            acc[mi][1] = __builtin_amdgcn_mfma_f32_16x16x32_bf16(af, bfrag[1], acc[mi][1], 0, 0, 0);
        }
    }

    float b0 = bl[wave * 32 + lr];
    float b1 = bl[wave * 32 + 16 + lr];
    int j0 = wave * 32 + lr;
#pragma unroll
    for (int mi = 0; mi < 8; ++mi) {
#pragma unroll
        for (int r = 0; r < 4; ++r) {
            int node = node0 + mi * 16 + quad * 4 + r;
            if (node < n_nodes) {
                float v0 = fmaxf(acc[mi][0][r] + b0, 0.f);
                float v1 = fmaxf(acc[mi][1][r] + b1, 0.f);
                out[(size_t)node * 128 + j0]      = f2b(v0);
                out[(size_t)node * 128 + j0 + 16] = f2b(v1);
                outf8[(size_t)node * 128 + j0]      = enc1_fp8(v0);
                outf8[(size_t)node * 128 + j0 + 16] = enc1_fp8(v1);
            }
        }
    }
}

// ---------------- layer-2 MFMA linear + Wout projection + last-block head ----
// logits[g,c] = (sum_{n in g} sum_j relu(h2[n,j]) * Wout[c,j]) / cnt + bout[c]
// Per-node dot in epilogue, LDS block reduction, 2 atomics per (block,graph),
// then the last block (device-scope ticket) computes log_softmax for all G.

__global__ __launch_bounds__(256) void k_linear2_head(
    const unsigned short* __restrict__ aggA, const unsigned short* __restrict__ xinA,
    const unsigned short* __restrict__ Wlb,  const float* __restrict__ bl,
    const unsigned short* __restrict__ Wrb,
    const int* __restrict__ batch, const int* __restrict__ gstart,
    const float* __restrict__ Wout, const float* __restrict__ bout,
    float* __restrict__ plog, int* __restrict__ counter,
    float* __restrict__ out, int n_nodes, int G) {
    constexpr int K = 128;
    constexpr int NCH = 8;
    __shared__ __align__(16) short As[128 * 32];   // 8 KB
    __shared__ int bb[128];
    __shared__ float2 red[256];
    __shared__ int isLast;

    int tid  = threadIdx.x;
    int lane = tid & 63;
    int wave = tid >> 6;
    int quad = lane >> 4;
    int lr   = lane & 15;
    int node0 = blockIdx.x * 128;

    if (tid < 128) {
        int n = node0 + tid;
        bb[tid] = (n < n_nodes) ? batch[n] : -1;
    }

    floatx4 acc[8][2];
#pragma unroll
    for (int mi = 0; mi < 8; ++mi)
#pragma unroll
        for (int ni = 0; ni < 2; ++ni)
            acc[mi][ni] = (floatx4){0.f, 0.f, 0.f, 0.f};

    int srow = tid >> 2;
    int sslot = tid & 3;

#pragma unroll
    for (int c = 0; c < NCH; ++c) {
        const unsigned short* srcA;
        const unsigned short* srcW;
        int kb;
        if (c < K / 32) { srcA = aggA; srcW = Wlb; kb = c * 32; }
        else            { srcA = xinA; srcW = Wrb; kb = c * 32 - K; }

        __syncthreads();
        {
            int n1 = node0 + srow;       if (n1 >= n_nodes) n1 = n_nodes - 1;
            int n2 = node0 + srow + 64;  if (n2 >= n_nodes) n2 = n_nodes - 1;
            uint4 v1 = *(const uint4*)(srcA + (size_t)n1 * K + kb + sslot * 8);
            uint4 v2 = *(const uint4*)(srcA + (size_t)n2 * K + kb + sslot * 8);
            *(uint4*)(&As[srow * 32 + sslot * 8]) = v1;
            *(uint4*)(&As[(srow + 64) * 32 + sslot * 8]) = v2;
        }
        __syncthreads();

        short8_t bfrag[2];
#pragma unroll
        for (int ni = 0; ni < 2; ++ni) {
            int j = wave * 32 + ni * 16 + lr;
            bfrag[ni] = *(const short8_t*)(srcW + (size_t)j * K + kb + quad * 8);
        }
#pragma unroll
        for (int mi = 0; mi < 8; ++mi) {
            short8_t af = *(const short8_t*)(&As[(mi * 16 + lr) * 32 + quad * 8]);
            acc[mi][0] = __builtin_amdgcn_mfma_f32_16x16x32_bf16(af, bfrag[0], acc[mi][0], 0, 0, 0);
            acc[mi][1] = __builtin_amdgcn_mfma_f32_16x16x32_bf16(af, bfrag[1], acc[mi][1], 0, 0, 0);
        }
    }

    // ---- epilogue: per-node Wout projection, per-graph block reduction ------
    float b0 = bl[wave * 32 + lr];
    float b1 = bl[wave * 32 + 16 + lr];
    int j0 = wave * 32 + lr;
    float w00 = Wout[j0];
    float w01 = Wout[j0 + 16];
    float w10 = Wout[128 + j0];
    float w11 = Wout[128 + j0 + 16];

    int gmin = batch[node0];
    int nlast = node0 + 127; if (nlast >= n_nodes) nlast = n_nodes - 1;
    int gmax = batch[nlast];

    for (int g = gmin; g <= gmax; ++g) {
        float d0 = 0.f, d1 = 0.f;
#pragma unroll
        for (int mi = 0; mi < 8; ++mi) {
#pragma unroll
            for (int r = 0; r < 4; ++r) {
                int li = mi * 16 + quad * 4 + r;
                if (bb[li] == g) {
                    float v0 = fmaxf(acc[mi][0][r] + b0, 0.f);
                    float v1 = fmaxf(acc[mi][1][r] + b1, 0.f);
                    d0 += v0 * w00 + v1 * w01;
                    d1 += v0 * w10 + v1 * w11;
                }
            }
        }
        red[tid] = make_float2(d0, d1);
        __syncthreads();
#pragma unroll
        for (int off = 128; off > 0; off >>= 1) {
            if (tid < off) {
                float2 o = red[tid + off];
                red[tid].x += o.x;
                red[tid].y += o.y;
            }
            __syncthreads();
        }
        if (tid == 0) {
            atomicAdd(&plog[g * 2 + 0], red[0].x);
            atomicAdd(&plog[g * 2 + 1], red[0].y);
        }
        __syncthreads();
    }

    // ---- last block computes log_softmax head -------------------------------
    __threadfence();
    if (tid == 0) {
        int t = atomicAdd(counter, 1);
        isLast = (t == (int)gridDim.x - 1) ? 1 : 0;
    }
    __syncthreads();
    if (isLast) {
        __threadfence();
        for (int g = tid; g < G; g += 256) {
            float l0 = atomicAdd(&plog[g * 2 + 0], 0.f);   // coherent read
            float l1 = atomicAdd(&plog[g * 2 + 1], 0.f);
            float cnt = (float)(gstart[g + 1] - gstart[g]);
            float inv = (cnt > 0.f) ? (1.f / cnt) : 1.f;
            l0 = l0 * inv + bout[0];
            l1 = l1 * inv + bout[1];
            float mx = fmaxf(l0, l1);
            float lse = mx + logf(expf(l0 - mx) + expf(l1 - mx));
            out[g * 2 + 0] = l0 - lse;
            out[g * 2 + 1] = l1 - lse;
        }
    }
}

// ---------------- launch -----------------------------------------------------

static inline size_t alignUp(size_t x, size_t a) { return (x + a - 1) & ~(a - 1); }

extern "C" void kernel_launch(void* const* d_in, const int* in_sizes, int n_in,
                              void* d_out, int out_size, void* d_ws, size_t ws_size,
                              hipStream_t stream) {
    const float* x    = (const float*)d_in[0];
    const int*   ei   = (const int*)d_in[1];
    const int*   batch= (const int*)d_in[2];
    const float* Wl1  = (const float*)d_in[3];
    const float* bl1  = (const float*)d_in[4];
    const float* Wr1  = (const float*)d_in[5];
    const float* Wl2  = (const float*)d_in[6];
    const float* bl2  = (const float*)d_in[7];
    const float* Wr2  = (const float*)d_in[8];
    const float* Wout = (const float*)d_in[9];
    const float* bout = (const float*)d_in[10];
    float* out = (float*)d_out;

    const int N = in_sizes[0] / 64;   // 100000 (must be < 2^23 for record packing)
    const int E = in_sizes[1] / 2;    // 1000000
    const int G = out_size / 2;       // 256

    const int* src = ei;
    const int* dst = ei + E;

    const int bHist = (E + EPB - 1) / EPB;     // 977
    const int NB    = (N + 511) >> BSH;        // 196 coarse buckets
    const int bCvtX = (N * 64 / 8 + 255) / 256;
    const int bCvtW = 192;
    const int NV1   = (N + 3) / 4;
    const int totalA = bHist + bCvtX + bCvtW + 2;

    // workspace layout
    char* ws = (char*)d_ws;
    size_t off = 0;
    int*   bhist     = (int*)(ws + off); off = alignUp(off + (size_t)bHist * 256 * 4, 256);
    int*   btot      = (int*)(ws + off); off = alignUp(off + (size_t)257 * 4, 256);
    int*   row_start = (int*)(ws + off); off = alignUp(off + (size_t)(N + 1) * 4, 256);
    int*   ebuf      = (int*)(ws + off); off = alignUp(off + (size_t)E * 4, 256);
    int*   csr_src   = (int*)(ws + off); off = alignUp(off + (size_t)E * 4, 256);
    int*   gstart    = (int*)(ws + off); off = alignUp(off + (size_t)(G + 1) * 4, 256);
    unsigned short* xb   = (unsigned short*)(ws + off); off = alignUp(off + (size_t)N * 64 * 2, 256);
    unsigned char*  xf8  = (unsigned char*)(ws + off);  off = alignUp(off + (size_t)N * 64, 256);
    unsigned short* wbuf = (unsigned short*)(ws + off); off = alignUp(off + (size_t)49152 * 2, 256);
    unsigned short* agg1 = (unsigned short*)(ws + off); off = alignUp(off + (size_t)N * 64 * 2, 256);
    unsigned short* h1   = (unsigned short*)(ws + off); off = alignUp(off + (size_t)N * 128 * 2, 256);
    unsigned char*  h1f8 = (unsigned char*)(ws + off);  off = alignUp(off + (size_t)N * 128, 256);
    unsigned short* agg2 = (unsigned short*)(ws + off); off = alignUp(off + (size_t)N * 128 * 2, 256);
    float*          plog = (float*)(ws + off); off = alignUp(off + (size_t)G * 2 * 4, 256);
    int*            counter = (int*)(ws + off); off = alignUp(off + 4, 256);
    (void)ws_size;

    unsigned short* Wl1b = wbuf;
    unsigned short* Wr1b = wbuf + 8192;
    unsigned short* Wl2b = wbuf + 16384;
    unsigned short* Wr2b = wbuf + 32768;

    // size the cooperative grid once (co-residency required for grid.sync)
    static int megaGrid = 0;   // 0 = unknown, -1 = disabled, >0 = grid size
    if (megaGrid == 0) {
        int occ = 0;
        hipError_t e1 = hipOccupancyMaxActiveBlocksPerMultiprocessor(&occ, k_mega, 256, 0);
        int cus = 0;
        hipDeviceProp_t prop;
        if (hipGetDeviceProperties(&prop, 0) == hipSuccess) cus = prop.multiProcessorCount;
        if (e1 != hipSuccess || occ <= 0 || cus <= 0) {
            megaGrid = -1;
        } else {
            long g = (long)occ * (long)cus;
            if (g > 2048) g = 2048;
            megaGrid = (int)g;
        }
    }

    bool coop_ok = false;
    if (megaGrid > 0) {
        MegaArgs MA;
        MA.src = src; MA.dst = dst; MA.E = E;
        MA.x = x; MA.xb = xb; MA.xf8 = xf8; MA.nX = N * 64;
        MA.Wl1 = Wl1; MA.Wr1 = Wr1; MA.Wl2 = Wl2; MA.Wr2 = Wr2;
        MA.wbuf = wbuf;
        MA.plog = plog; MA.counter = counter;
        MA.batch = batch; MA.gstart = gstart; MA.N = N; MA.G = G;
        MA.bhist = bhist; MA.btot = btot; MA.ebuf = ebuf;
        MA.row_start = row_start; MA.csr_src = csr_src;
        MA.agg1 = agg1;
        MA.bHist = bHist; MA.bCvtX = bCvtX; MA.bCvtW = bCvtW;
        MA.NB = NB; MA.NV1 = NV1;
        void* params[1] = { (void*)&MA };
        hipError_t err = hipLaunchCooperativeKernel(k_mega, dim3(megaGrid), dim3(256),
                                                    params, 0u, stream);
        if (err == hipSuccess) {
            coop_ok = true;
        } else {
            megaGrid = -1;   // never retry cooperative on this device
        }
    }

    if (!coop_ok) {
        // fallback: split preprocessing chain (R16 structure)
        k_phase_a_fb<<<totalA, 256, 0, stream>>>(
            dst, bhist, E, x, xb, xf8, N * 64,
            Wl1, Wr1, Wl2, Wr2, wbuf, plog, counter,
            batch, gstart, N, G, bHist, bCvtX, bCvtW);
        k_scan_bh_fb<<<256, 256, 0, stream>>>(bhist, btot, bHist);
        k_scatter_fb<<<bHist, 256, 0, stream>>>(src, dst, bhist, btot, ebuf, E);
        k_bucket_fb<<<NB, 256, 0, stream>>>(ebuf, btot, row_start, csr_src, N, NB);
        k_gather1_fb<<<NV1, 256, 0, stream>>>(xf8, row_start, csr_src, agg1, N);
    }

    // layer 1 linear: emits h1 bf16 + h1f8 fp8
    k_linear1<<<(N + 127) / 128, 256, 0, stream>>>(
        agg1, xb, Wl1b, bl1, Wr1b, h1, h1f8, N);

    // layer 2 gather
    k_gather2<<<NV1, 256, 0, stream>>>(h1f8, row_start, csr_src, agg2, N);

    // layer 2 linear + Wout projection + last-block log_softmax head
    k_linear2_head<<<(N + 127) / 128, 256, 0, stream>>>(
        agg2, h1, Wl2b, bl2, Wr2b, batch, gstart, Wout, bout,
        plog, counter, out, N, G);
}

// Round 4
// 297.240 us; speedup vs baseline: 4.3479x; 4.3479x over previous
//
#include <hip/hip_runtime.h>
#include <hip/hip_bf16.h>
#include <math.h>

typedef short short8_t __attribute__((ext_vector_type(8)));
typedef float floatx4  __attribute__((ext_vector_type(4)));
typedef float floatx2  __attribute__((ext_vector_type(2)));
typedef unsigned int uint;

#define EPB 1024   // edges per histogram/scatter block
#define BSH 9      // 512 nodes per coarse bucket

// ---------------- bf16 helpers (RNE) ----------------------------------------

__device__ inline unsigned short f2b(float f) {
    uint u = __float_as_uint(f);
    u += 0x7fff + ((u >> 16) & 1);
    return (unsigned short)(u >> 16);
}
__device__ inline uint pack2(float a, float b) {
    return (uint)f2b(a) | ((uint)f2b(b) << 16);
}

// ---------------- fp8 (e4m3) helpers -----------------------------------------

__device__ inline uint enc4_fp8(float f0, float f1, float f2, float f3) {
    uint v = __builtin_amdgcn_cvt_pk_fp8_f32(f0, f1, 0, false);
    v = __builtin_amdgcn_cvt_pk_fp8_f32(f2, f3, v, true);
    return v;
}
__device__ inline unsigned char enc1_fp8(float f) {
    return (unsigned char)(__builtin_amdgcn_cvt_pk_fp8_f32(f, f, 0, false) & 0xff);
}

// Lesson ledger:
//  R10/R13: GLOBAL atomic histogram pinned ~43-50us — replaced by LDS hist.
//  R12: co-scheduling light branches in one grid is free.
//  R11/R14/R15: a latency-bound phase inherits a fused kernel's worst-phase
//       occupancy — per-BLOCK fusion of gather into MFMA collapsed (139us).
//  R9: keep scatter targets packed (L2-resident).
//  R16: split structure, 9 dispatches -> 258us; work models sum ~120us.
//  R17 (FAILED): cooperative mega-kernel. grid.sync() on 8-XCD gfx950 costs
//       ~350us EACH (cross-XCD L2 writeback/invalidate + 2048-block spin):
//       k_mega 1520us, Occ 98%, VALU 1.8%, HBM 1.2% — waves parked in sync.
//       A grid barrier inside a kernel is STRICTLY WORSE than a kernel
//       boundary here. Never use coop grid.sync on this platform.
//  R18 (this round): R16 structure + keep the HW-validated linear2_head
//       fusion (head dispatch + pooled[G][128] gone). 8 dispatches.

// ---------------- shared device phase bodies ---------------------------------

__device__ inline void scan256(int* ss, int t) {
#pragma unroll
    for (int off = 1; off < 256; off <<= 1) {
        int u = (t >= off) ? ss[t - off] : 0;
        __syncthreads();
        ss[t] += u;
        __syncthreads();
    }
}

// phase A virtual block: hist | cvt_x | cvt_w | zero(plog,counter) | gstart
__device__ inline void phaseA_iter(
    int vb, int tid, int* h,
    const int* __restrict__ dst, int* __restrict__ bhist, int E,
    const float* __restrict__ x, unsigned short* __restrict__ xb,
    unsigned char* __restrict__ xf8, int nX,
    const float* __restrict__ Wl1, const float* __restrict__ Wr1,
    const float* __restrict__ Wl2, const float* __restrict__ Wr2,
    unsigned short* __restrict__ wbuf,
    float* __restrict__ plog, int* __restrict__ counter,
    const int* __restrict__ batch, int* __restrict__ gstart, int N, int G,
    int bHist, int bCvtX, int bCvtW) {
    if (vb < bHist) {
        h[tid] = 0;
        __syncthreads();
        int e = vb * EPB + tid * 4;
        if (e + 3 < E) {
            int4 d4 = *(const int4*)(dst + e);
            atomicAdd(&h[d4.x >> BSH], 1);
            atomicAdd(&h[d4.y >> BSH], 1);
            atomicAdd(&h[d4.z >> BSH], 1);
            atomicAdd(&h[d4.w >> BSH], 1);
        } else {
            for (int k = e; k < E; ++k) atomicAdd(&h[dst[k] >> BSH], 1);
        }
        __syncthreads();
        bhist[(size_t)vb * 256 + tid] = h[tid];
    } else if (vb < bHist + bCvtX) {
        int i = ((vb - bHist) * 256 + tid) * 8;
        if (i < nX) {
            float4 v0 = *(const float4*)(x + i);
            float4 v1 = *(const float4*)(x + i + 4);
            uint4 ob;
            ob.x = pack2(v0.x, v0.y);
            ob.y = pack2(v0.z, v0.w);
            ob.z = pack2(v1.x, v1.y);
            ob.w = pack2(v1.z, v1.w);
            *(uint4*)(xb + i) = ob;
            uint2 of;
            of.x = enc4_fp8(v0.x, v0.y, v0.z, v0.w);
            of.y = enc4_fp8(v1.x, v1.y, v1.z, v1.w);
            *(uint2*)(xf8 + i) = of;
        }
    } else if (vb < bHist + bCvtX + bCvtW) {
        int i = (vb - bHist - bCvtX) * 256 + tid;
        if (i < 49152) {
            float v;
            if (i < 8192)       v = Wl1[i];
            else if (i < 16384) v = Wr1[i - 8192];
            else if (i < 32768) v = Wl2[i - 16384];
            else                v = Wr2[i - 32768];
            wbuf[i] = f2b(v);
        }
    } else if (vb == bHist + bCvtX + bCvtW) {
        for (int i = tid; i < 2 * G; i += 256) plog[i] = 0.f;
        if (tid == 0) *counter = 0;
    } else {
        for (int g = tid; g <= G; g += 256) {
            if (g == G) { gstart[G] = N; continue; }
            int lo = 0, hi = N;
            while (lo < hi) {
                int mid = (lo + hi) >> 1;
                if (batch[mid] < g) lo = mid + 1; else hi = mid;
            }
            gstart[g] = lo;
        }
    }
}

__global__ __launch_bounds__(256) void k_phase_a(
    const int* __restrict__ dst, int* __restrict__ bhist, int E,
    const float* __restrict__ x, unsigned short* __restrict__ xb,
    unsigned char* __restrict__ xf8, int nX,
    const float* __restrict__ Wl1, const float* __restrict__ Wr1,
    const float* __restrict__ Wl2, const float* __restrict__ Wr2,
    unsigned short* __restrict__ wbuf,
    float* __restrict__ plog, int* __restrict__ counter,
    const int* __restrict__ batch, int* __restrict__ gstart, int N, int G,
    int bHist, int bCvtX, int bCvtW) {
    __shared__ int h[256];
    phaseA_iter(blockIdx.x, threadIdx.x, h, dst, bhist, E, x, xb, xf8, nX,
                Wl1, Wr1, Wl2, Wr2, wbuf, plog, counter, batch, gstart, N, G,
                bHist, bCvtX, bCvtW);
}

// column scan: for bucket k, exclusive-prefix bhist[:,k] over blocks; btot[k]=total
__global__ __launch_bounds__(256) void k_scan_bh(int* __restrict__ bhist,
                                                 int* __restrict__ btot, int nb) {
    __shared__ int ss[256];
    int k = blockIdx.x;
    int t = threadIdx.x;
    int b0 = t * 4;
    int v[4];
    int sum = 0;
#pragma unroll
    for (int i = 0; i < 4; ++i) {
        int b = b0 + i;
        v[i] = (b < nb) ? bhist[(size_t)b * 256 + k] : 0;
        sum += v[i];
    }
    ss[t] = sum;
    __syncthreads();
    scan256(ss, t);
    int run = ss[t] - sum;
#pragma unroll
    for (int i = 0; i < 4; ++i) {
        int b = b0 + i;
        if (b < nb) { bhist[(size_t)b * 256 + k] = run; run += v[i]; }
    }
    if (t == 0) btot[k] = ss[255];
}

// scatter edges into bucket-grouped ebuf; positions via LDS cursors.
// bucket bases recomputed locally from btot. record = (dst&511)<<23 | src
__global__ __launch_bounds__(256) void k_scatter_b(
    const int* __restrict__ src, const int* __restrict__ dst,
    const int* __restrict__ bhist, const int* __restrict__ btot,
    int* __restrict__ ebuf, int E) {
    __shared__ int ss[256];
    __shared__ int lbase[256];
    int b = blockIdx.x;
    int t = threadIdx.x;
    int v = btot[t];
    ss[t] = v;
    __syncthreads();
    scan256(ss, t);
    lbase[t] = (ss[t] - v) + bhist[(size_t)b * 256 + t];
    __syncthreads();
    int e = b * EPB + t * 4;
    if (e + 3 < E) {
        int4 d4 = *(const int4*)(dst + e);
        int4 s4 = *(const int4*)(src + e);
        int k, p;
        k = d4.x >> BSH; p = atomicAdd(&lbase[k], 1); ebuf[p] = ((d4.x & 511) << 23) | s4.x;
        k = d4.y >> BSH; p = atomicAdd(&lbase[k], 1); ebuf[p] = ((d4.y & 511) << 23) | s4.y;
        k = d4.z >> BSH; p = atomicAdd(&lbase[k], 1); ebuf[p] = ((d4.z & 511) << 23) | s4.z;
        k = d4.w >> BSH; p = atomicAdd(&lbase[k], 1); ebuf[p] = ((d4.w & 511) << 23) | s4.w;
    } else {
        for (int q = e; q < E; ++q) {
            int d = dst[q];
            int p = atomicAdd(&lbase[d >> BSH], 1);
            ebuf[p] = ((d & 511) << 23) | src[q];
        }
    }
}

// per-bucket counting sort: 512-bin LDS histogram + scan -> row_start + csr_src
__global__ __launch_bounds__(256) void k_bucket_csr(
    const int* __restrict__ ebuf, const int* __restrict__ btot,
    int* __restrict__ row_start, int* __restrict__ csr_src, int N, int NB) {
    __shared__ int ss[256];
    __shared__ int bbS[257];
    __shared__ int h2[512];
    int k = blockIdx.x;
    int t = threadIdx.x;
    int v = btot[t];
    ss[t] = v;
    __syncthreads();
    scan256(ss, t);
    bbS[t] = ss[t] - v;
    if (t == 255) bbS[256] = ss[255];
    __syncthreads();
    int s = bbS[k], e = bbS[k + 1];
    int node0 = k << BSH;
    int nn = N - node0; if (nn > 512) nn = 512;
    if (k == NB - 1 && t == 0) row_start[node0 + nn] = e;
    h2[t] = 0; h2[t + 256] = 0;
    __syncthreads();
    for (int i = s + t; i < e; i += 256)
        atomicAdd(&h2[((uint)ebuf[i]) >> 23], 1);
    __syncthreads();
    int a0 = h2[2 * t], a1 = h2[2 * t + 1];
    int ps = a0 + a1;
    ss[t] = ps;
    __syncthreads();
    scan256(ss, t);
    int base = ss[t] - ps;
    h2[2 * t] = base;
    h2[2 * t + 1] = base + a0;
    __syncthreads();
    int rs0 = h2[t];
    int rs1 = h2[t + 256];
    __syncthreads();
    if (t < nn)       row_start[node0 + t]       = s + rs0;
    if (t + 256 < nn) row_start[node0 + t + 256] = s + rs1;
    for (int i = s + t; i < e; i += 256) {
        int rec = ebuf[i];
        int j = ((uint)rec) >> 23;
        int pos = atomicAdd(&h2[j], 1);
        csr_src[s + pos] = rec & 0x7FFFFF;
    }
}

// ---------------- mean aggregation (fp8 in, bf16 out, fp32 accumulate) -------
// 1 node per 64-lane wave, no LDS, full occupancy: latency hidden by waves.

#define ACCF8(v)                                                        \
    { floatx2 f = __builtin_amdgcn_cvt_pk_f32_fp8((v).x, false);        \
      a[0] += f[0]; a[1] += f[1];                                       \
      f = __builtin_amdgcn_cvt_pk_f32_fp8((v).x, true);                 \
      a[2] += f[0]; a[3] += f[1];                                       \
      f = __builtin_amdgcn_cvt_pk_f32_fp8((v).y, false);                \
      a[4] += f[0]; a[5] += f[1];                                       \
      f = __builtin_amdgcn_cvt_pk_f32_fp8((v).y, true);                 \
      a[6] += f[0]; a[7] += f[1]; }

// K=64: row = 64 B fp8. 8 edge-slots x 8 lanes x uint2; 2-deep unroll.
__global__ void k_gather1(const unsigned char* __restrict__ xf8,
                          const int* __restrict__ row_start,
                          const int* __restrict__ csr_src,
                          unsigned short* __restrict__ agg, int n_nodes) {
    int tid = threadIdx.x;
    int node = blockIdx.x * 4 + (tid >> 6);
    if (node >= n_nodes) return;
    int lane = tid & 63;
    int grp = lane >> 3;
    int lp  = lane & 7;
    int s = row_start[node];
    int e = row_start[node + 1];
    float a[8];
#pragma unroll
    for (int q = 0; q < 8; ++q) a[q] = 0.f;
    int i = s + grp;
    for (; i + 8 < e; i += 16) {
        int u0 = csr_src[i];
        int u1 = csr_src[i + 8];
        uint2 v0 = *(const uint2*)(xf8 + (size_t)u0 * 64 + lp * 8);
        uint2 v1 = *(const uint2*)(xf8 + (size_t)u1 * 64 + lp * 8);
        ACCF8(v0);
        ACCF8(v1);
    }
    if (i < e) {
        int u0 = csr_src[i];
        uint2 v0 = *(const uint2*)(xf8 + (size_t)u0 * 64 + lp * 8);
        ACCF8(v0);
    }
#pragma unroll
    for (int q = 0; q < 8; ++q) {
        a[q] += __shfl_xor(a[q], 8);
        a[q] += __shfl_xor(a[q], 16);
        a[q] += __shfl_xor(a[q], 32);
    }
    if (grp == 0) {
        int d = e - s;
        float scale = (d > 0) ? (1.f / (float)d) : 1.f;
        uint4 o;
        o.x = pack2(a[0] * scale, a[1] * scale);
        o.y = pack2(a[2] * scale, a[3] * scale);
        o.z = pack2(a[4] * scale, a[5] * scale);
        o.w = pack2(a[6] * scale, a[7] * scale);
        *(uint4*)(agg + (size_t)node * 64 + lp * 8) = o;
    }
}

// K=128: row = 128 B fp8. 4 edge-slots x 16 lanes x uint2; 2-deep unroll.
__global__ void k_gather2(const unsigned char* __restrict__ h1f8,
                          const int* __restrict__ row_start,
                          const int* __restrict__ csr_src,
                          unsigned short* __restrict__ agg, int n_nodes) {
    int tid = threadIdx.x;
    int node = blockIdx.x * 4 + (tid >> 6);
    if (node >= n_nodes) return;
    int lane = tid & 63;
    int grp = lane >> 4;
    int lp  = lane & 15;
    int s = row_start[node];
    int e = row_start[node + 1];
    float a[8];
#pragma unroll
    for (int q = 0; q < 8; ++q) a[q] = 0.f;
    int i = s + grp;
    for (; i + 4 < e; i += 8) {
        int u0 = csr_src[i];
        int u1 = csr_src[i + 4];
        uint2 v0 = *(const uint2*)(h1f8 + (size_t)u0 * 128 + lp * 8);
        uint2 v1 = *(const uint2*)(h1f8 + (size_t)u1 * 128 + lp * 8);
        ACCF8(v0);
        ACCF8(v1);
    }
    if (i < e) {
        int u0 = csr_src[i];
        uint2 v0 = *(const uint2*)(h1f8 + (size_t)u0 * 128 + lp * 8);
        ACCF8(v0);
    }
#pragma unroll
    for (int q = 0; q < 8; ++q) {
        a[q] += __shfl_xor(a[q], 16);
        a[q] += __shfl_xor(a[q], 32);
    }
    if (grp == 0) {
        int d = e - s;
        float scale = (d > 0) ? (1.f / (float)d) : 1.f;
        uint4 o;
        o.x = pack2(a[0] * scale, a[1] * scale);
        o.y = pack2(a[2] * scale, a[3] * scale);
        o.z = pack2(a[4] * scale, a[5] * scale);
        o.w = pack2(a[6] * scale, a[7] * scale);
        *(uint4*)(agg + (size_t)node * 128 + lp * 8) = o;
    }
}

// ---------------- layer-1 MFMA linear: relu(agg@Wl.T + bl + x@Wr.T) ----------

__global__ __launch_bounds__(256) void k_linear1(
    const unsigned short* __restrict__ aggA, const unsigned short* __restrict__ xinA,
    const unsigned short* __restrict__ Wlb,  const float* __restrict__ bl,
    const unsigned short* __restrict__ Wrb,  unsigned short* __restrict__ out,
    unsigned char* __restrict__ outf8, int n_nodes) {
    constexpr int K = 64;
    constexpr int NCH = 4;
    __shared__ __align__(16) short As[128 * 32];   // 8 KB

    int tid  = threadIdx.x;
    int lane = tid & 63;
    int wave = tid >> 6;
    int quad = lane >> 4;
    int lr   = lane & 15;
    int node0 = blockIdx.x * 128;

    floatx4 acc[8][2];
#pragma unroll
    for (int mi = 0; mi < 8; ++mi)
#pragma unroll
        for (int ni = 0; ni < 2; ++ni)
            acc[mi][ni] = (floatx4){0.f, 0.f, 0.f, 0.f};

    int srow = tid >> 2;
    int sslot = tid & 3;

#pragma unroll
    for (int c = 0; c < NCH; ++c) {
        const unsigned short* srcA;
        const unsigned short* srcW;
        int kb;
        if (c < K / 32) { srcA = aggA; srcW = Wlb; kb = c * 32; }
        else            { srcA = xinA; srcW = Wrb; kb = c * 32 - K; }

        __syncthreads();
        {
            int n1 = node0 + srow;       if (n1 >= n_nodes) n1 = n_nodes - 1;
            int n2 = node0 + srow + 64;  if (n2 >= n_nodes) n2 = n_nodes - 1;
            uint4 v1 = *(const uint4*)(srcA + (size_t)n1 * K + kb + sslot * 8);
            uint4 v2 = *(const uint4*)(srcA + (size_t)n2 * K + kb + sslot * 8);
            *(uint4*)(&As[srow * 32 + sslot * 8]) = v1;
            *(uint4*)(&As[(srow + 64) * 32 + sslot * 8]) = v2;
        }
        __syncthreads();

        short8_t bfrag[2];
#pragma unroll
        for (int ni = 0; ni < 2; ++ni) {
            int j = wave * 32 + ni * 16 + lr;
            bfrag[ni] = *(const short8_t*)(srcW + (size_t)j * K + kb + quad * 8);
        }
#pragma unroll
        for (int mi = 0; mi < 8; ++mi) {
            short8_t af = *(const short8_t*)(&As[(mi * 16 + lr) * 32 + quad * 8]);
            acc[mi][0] = __builtin_amdgcn_mfma_f32_16x16x32_bf16(af, bfrag[0], acc[mi][0], 0, 0, 0);
            acc[mi][1] = __builtin_amdgcn_mfma_f32_16x16x32_bf16(af, bfrag[1], acc[mi][1], 0, 0, 0);
        }
    }

    float b0 = bl[wave * 32 + lr];
    float b1 = bl[wave * 32 + 16 + lr];
    int j0 = wave * 32 + lr;
#pragma unroll
    for (int mi = 0; mi < 8; ++mi) {
#pragma unroll
        for (int r = 0; r < 4; ++r) {
            int node = node0 + mi * 16 + quad * 4 + r;
            if (node < n_nodes) {
                float v0 = fmaxf(acc[mi][0][r] + b0, 0.f);
                float v1 = fmaxf(acc[mi][1][r] + b1, 0.f);
                out[(size_t)node * 128 + j0]      = f2b(v0);
                out[(size_t)node * 128 + j0 + 16] = f2b(v1);
                outf8[(size_t)node * 128 + j0]      = enc1_fp8(v0);
                outf8[(size_t)node * 128 + j0 + 16] = enc1_fp8(v1);
            }
        }
    }
}

// ---------------- layer-2 MFMA linear + Wout projection + last-block head ----
// logits[g,c] = (sum_{n in g} sum_j relu(h2[n,j]) * Wout[c,j]) / cnt + bout[c]
// Per-node dot in epilogue, LDS block reduction, 2 atomics per (block,graph),
// then the last block (device-scope ticket) computes log_softmax for all G.
// HW-validated in R3 (ran in the passing timed run).

__global__ __launch_bounds__(256) void k_linear2_head(
    const unsigned short* __restrict__ aggA, const unsigned short* __restrict__ xinA,
    const unsigned short* __restrict__ Wlb,  const float* __restrict__ bl,
    const unsigned short* __restrict__ Wrb,
    const int* __restrict__ batch, const int* __restrict__ gstart,
    const float* __restrict__ Wout, const float* __restrict__ bout,
    float* __restrict__ plog, int* __restrict__ counter,
    float* __restrict__ out, int n_nodes, int G) {
    constexpr int K = 128;
    constexpr int NCH = 8;
    __shared__ __align__(16) short As[128 * 32];   // 8 KB
    __shared__ int bb[128];
    __shared__ float2 red[256];
    __shared__ int isLast;

    int tid  = threadIdx.x;
    int lane = tid & 63;
    int wave = tid >> 6;
    int quad = lane >> 4;
    int lr   = lane & 15;
    int node0 = blockIdx.x * 128;

    if (tid < 128) {
        int n = node0 + tid;
        bb[tid] = (n < n_nodes) ? batch[n] : -1;
    }

    floatx4 acc[8][2];
#pragma unroll
    for (int mi = 0; mi < 8; ++mi)
#pragma unroll
        for (int ni = 0; ni < 2; ++ni)
            acc[mi][ni] = (floatx4){0.f, 0.f, 0.f, 0.f};

    int srow = tid >> 2;
    int sslot = tid & 3;

#pragma unroll
    for (int c = 0; c < NCH; ++c) {
        const unsigned short* srcA;
        const unsigned short* srcW;
        int kb;
        if (c < K / 32) { srcA = aggA; srcW = Wlb; kb = c * 32; }
        else            { srcA = xinA; srcW = Wrb; kb = c * 32 - K; }

        __syncthreads();
        {
            int n1 = node0 + srow;       if (n1 >= n_nodes) n1 = n_nodes - 1;
            int n2 = node0 + srow + 64;  if (n2 >= n_nodes) n2 = n_nodes - 1;
            uint4 v1 = *(const uint4*)(srcA + (size_t)n1 * K + kb + sslot * 8);
            uint4 v2 = *(const uint4*)(srcA + (size_t)n2 * K + kb + sslot * 8);
            *(uint4*)(&As[srow * 32 + sslot * 8]) = v1;
            *(uint4*)(&As[(srow + 64) * 32 + sslot * 8]) = v2;
        }
        __syncthreads();

        short8_t bfrag[2];
#pragma unroll
        for (int ni = 0; ni < 2; ++ni) {
            int j = wave * 32 + ni * 16 + lr;
            bfrag[ni] = *(const short8_t*)(srcW + (size_t)j * K + kb + quad * 8);
        }
#pragma unroll
        for (int mi = 0; mi < 8; ++mi) {
            short8_t af = *(const short8_t*)(&As[(mi * 16 + lr) * 32 + quad * 8]);
            acc[mi][0] = __builtin_amdgcn_mfma_f32_16x16x32_bf16(af, bfrag[0], acc[mi][0], 0, 0, 0);
            acc[mi][1] = __builtin_amdgcn_mfma_f32_16x16x32_bf16(af, bfrag[1], acc[mi][1], 0, 0, 0);
        }
    }

    // ---- epilogue: per-node Wout projection, per-graph block reduction ------
    float b0 = bl[wave * 32 + lr];
    float b1 = bl[wave * 32 + 16 + lr];
    int j0 = wave * 32 + lr;
    float w00 = Wout[j0];
    float w01 = Wout[j0 + 16];
    float w10 = Wout[128 + j0];
    float w11 = Wout[128 + j0 + 16];

    int gmin = batch[node0];
    int nlast = node0 + 127; if (nlast >= n_nodes) nlast = n_nodes - 1;
    int gmax = batch[nlast];

    for (int g = gmin; g <= gmax; ++g) {
        float d0 = 0.f, d1 = 0.f;
#pragma unroll
        for (int mi = 0; mi < 8; ++mi) {
#pragma unroll
            for (int r = 0; r < 4; ++r) {
                int li = mi * 16 + quad * 4 + r;
                if (bb[li] == g) {
                    float v0 = fmaxf(acc[mi][0][r] + b0, 0.f);
                    float v1 = fmaxf(acc[mi][1][r] + b1, 0.f);
                    d0 += v0 * w00 + v1 * w01;
                    d1 += v0 * w10 + v1 * w11;
                }
            }
        }
        red[tid] = make_float2(d0, d1);
        __syncthreads();
#pragma unroll
        for (int off = 128; off > 0; off >>= 1) {
            if (tid < off) {
                float2 o = red[tid + off];
                red[tid].x += o.x;
                red[tid].y += o.y;
            }
            __syncthreads();
        }
        if (tid == 0) {
            atomicAdd(&plog[g * 2 + 0], red[0].x);
            atomicAdd(&plog[g * 2 + 1], red[0].y);
        }
        __syncthreads();
    }

    // ---- last block computes log_softmax head -------------------------------
    __threadfence();
    if (tid == 0) {
        int t = atomicAdd(counter, 1);
        isLast = (t == (int)gridDim.x - 1) ? 1 : 0;
    }
    __syncthreads();
    if (isLast) {
        __threadfence();
        for (int g = tid; g < G; g += 256) {
            float l0 = atomicAdd(&plog[g * 2 + 0], 0.f);   // coherent read
            float l1 = atomicAdd(&plog[g * 2 + 1], 0.f);
            float cnt = (float)(gstart[g + 1] - gstart[g]);
            float inv = (cnt > 0.f) ? (1.f / cnt) : 1.f;
            l0 = l0 * inv + bout[0];
            l1 = l1 * inv + bout[1];
            float mx = fmaxf(l0, l1);
            float lse = mx + logf(expf(l0 - mx) + expf(l1 - mx));
            out[g * 2 + 0] = l0 - lse;
            out[g * 2 + 1] = l1 - lse;
        }
    }
}

// ---------------- launch -----------------------------------------------------

static inline size_t alignUp(size_t x, size_t a) { return (x + a - 1) & ~(a - 1); }

extern "C" void kernel_launch(void* const* d_in, const int* in_sizes, int n_in,
                              void* d_out, int out_size, void* d_ws, size_t ws_size,
                              hipStream_t stream) {
    const float* x    = (const float*)d_in[0];
    const int*   ei   = (const int*)d_in[1];
    const int*   batch= (const int*)d_in[2];
    const float* Wl1  = (const float*)d_in[3];
    const float* bl1  = (const float*)d_in[4];
    const float* Wr1  = (const float*)d_in[5];
    const float* Wl2  = (const float*)d_in[6];
    const float* bl2  = (const float*)d_in[7];
    const float* Wr2  = (const float*)d_in[8];
    const float* Wout = (const float*)d_in[9];
    const float* bout = (const float*)d_in[10];
    float* out = (float*)d_out;

    const int N = in_sizes[0] / 64;   // 100000 (must be < 2^23 for record packing)
    const int E = in_sizes[1] / 2;    // 1000000
    const int G = out_size / 2;       // 256

    const int* src = ei;
    const int* dst = ei + E;

    const int bHist = (E + EPB - 1) / EPB;     // 977
    const int NB    = (N + 511) >> BSH;        // 196 coarse buckets
    const int bCvtX = (N * 64 / 8 + 255) / 256;
    const int bCvtW = 192;
    const int NV1   = (N + 3) / 4;

    // workspace layout
    char* ws = (char*)d_ws;
    size_t off = 0;
    int*   bhist     = (int*)(ws + off); off = alignUp(off + (size_t)bHist * 256 * 4, 256);
    int*   btot      = (int*)(ws + off); off = alignUp(off + (size_t)257 * 4, 256);
    int*   row_start = (int*)(ws + off); off = alignUp(off + (size_t)(N + 1) * 4, 256);
    int*   ebuf      = (int*)(ws + off); off = alignUp(off + (size_t)E * 4, 256);
    int*   csr_src   = (int*)(ws + off); off = alignUp(off + (size_t)E * 4, 256);
    int*   gstart    = (int*)(ws + off); off = alignUp(off + (size_t)(G + 1) * 4, 256);
    unsigned short* xb   = (unsigned short*)(ws + off); off = alignUp(off + (size_t)N * 64 * 2, 256);
    unsigned char*  xf8  = (unsigned char*)(ws + off);  off = alignUp(off + (size_t)N * 64, 256);
    unsigned short* wbuf = (unsigned short*)(ws + off); off = alignUp(off + (size_t)49152 * 2, 256);
    unsigned short* agg1 = (unsigned short*)(ws + off); off = alignUp(off + (size_t)N * 64 * 2, 256);
    unsigned short* h1   = (unsigned short*)(ws + off); off = alignUp(off + (size_t)N * 128 * 2, 256);
    unsigned char*  h1f8 = (unsigned char*)(ws + off);  off = alignUp(off + (size_t)N * 128, 256);
    unsigned short* agg2 = (unsigned short*)(ws + off); off = alignUp(off + (size_t)N * 128 * 2, 256);
    float*          plog = (float*)(ws + off); off = alignUp(off + (size_t)G * 2 * 4, 256);
    int*            counter = (int*)(ws + off); off = alignUp(off + 4, 256);
    (void)ws_size;

    unsigned short* Wl1b = wbuf;
    unsigned short* Wr1b = wbuf + 8192;
    unsigned short* Wl2b = wbuf + 16384;
    unsigned short* Wr2b = wbuf + 32768;

    // phase A: LDS bucket histogram + cvt_x + cvt_w + zero(plog) + graph bounds
    k_phase_a<<<bHist + bCvtX + bCvtW + 2, 256, 0, stream>>>(
        dst, bhist, E,
        x, xb, xf8, N * 64,
        Wl1, Wr1, Wl2, Wr2, wbuf,
        plog, counter,
        batch, gstart, N, G,
        bHist, bCvtX, bCvtW);

    // bucket scans + bucket-grouped scatter + per-bucket counting sort
    k_scan_bh<<<256, 256, 0, stream>>>(bhist, btot, bHist);
    k_scatter_b<<<bHist, 256, 0, stream>>>(src, dst, bhist, btot, ebuf, E);
    k_bucket_csr<<<NB, 256, 0, stream>>>(ebuf, btot, row_start, csr_src, N, NB);

    // layer 1: gather (fp8) -> MFMA linear (emits h1 bf16 + h1f8 fp8)
    k_gather1<<<NV1, 256, 0, stream>>>(xf8, row_start, csr_src, agg1, N);
    k_linear1<<<(N + 127) / 128, 256, 0, stream>>>(
        agg1, xb, Wl1b, bl1, Wr1b, h1, h1f8, N);

    // layer 2: gather -> MFMA linear + Wout projection + last-block head
    k_gather2<<<NV1, 256, 0, stream>>>(h1f8, row_start, csr_src, agg2, N);
    k_linear2_head<<<(N + 127) / 128, 256, 0, stream>>>(
        agg2, h1, Wl2b, bl2, Wr2b, batch, gstart, Wout, bout,
        plog, counter, out, N, G);
}

// Round 5
// 255.943 us; speedup vs baseline: 5.0494x; 1.1614x over previous
//
#include <hip/hip_runtime.h>
#include <hip/hip_bf16.h>
#include <math.h>

typedef short short8_t __attribute__((ext_vector_type(8)));
typedef float floatx4  __attribute__((ext_vector_type(4)));
typedef float floatx2  __attribute__((ext_vector_type(2)));
typedef unsigned int uint;

#define EPB 1024   // edges per histogram/scatter block
#define BSH 9      // 512 nodes per coarse bucket

// ---------------- bf16 helpers (RNE) ----------------------------------------

__device__ inline unsigned short f2b(float f) {
    uint u = __float_as_uint(f);
    u += 0x7fff + ((u >> 16) & 1);
    return (unsigned short)(u >> 16);
}
__device__ inline uint pack2(float a, float b) {
    return (uint)f2b(a) | ((uint)f2b(b) << 16);
}
__device__ inline float blo(uint v) { return __uint_as_float(v << 16); }
__device__ inline float bhi(uint v) { return __uint_as_float(v & 0xffff0000u); }

// ---------------- fp8 (e4m3) helpers -----------------------------------------

__device__ inline uint enc4_fp8(float f0, float f1, float f2, float f3) {
    uint v = __builtin_amdgcn_cvt_pk_fp8_f32(f0, f1, 0, false);
    v = __builtin_amdgcn_cvt_pk_fp8_f32(f2, f3, v, true);
    return v;
}
__device__ inline unsigned char enc1_fp8(float f) {
    return (unsigned char)(__builtin_amdgcn_cvt_pk_fp8_f32(f, f, 0, false) & 0xff);
}

// Lesson ledger:
//  R10/R13: GLOBAL atomic histogram pinned ~43-50us — replaced by LDS hist.
//  R12: co-scheduling light branches in one grid is free.
//  R11/R14/R15: a latency-bound phase inherits a fused kernel's worst-phase
//       occupancy — per-BLOCK fusion of gather into MFMA collapsed (139us).
//  R9: keep scatter targets packed (L2-resident).
//  R16: split structure, 9 dispatches -> 258us.
//  R17 (FAILED): coop grid.sync costs ~350us EACH on 8-XCD gfx950. Never.
//  R18 (FAILED): head-in-epilogue via per-graph LDS tree + __threadfence +
//       ticket = +40us (k_linear2_head 72us, MfmaUtil 3%). Device-scope
//       fences/tickets per block are mini grid.syncs. ALSO LEARNED: a linear
//       kernel is ~35-40us, not ~12 — the 8-chunk staging exposes 8 global
//       latencies (load->drain->barrier per chunk) at ~3 blocks/CU.
//  R19 (this round): revert to R2 epilogue (running sums + atomics to
//       pooled[G][128], separate tiny k_head). Replace chunked staging with
//       FULL-TILE single-barrier staging: both 128xK operands in LDS at once
//       (LDS is 160KB/CU, we used 8), all loads in flight together, ONE
//       barrier, then all MFMAs sync-free. Rows padded to K+8 for bank spread.

// ---------------- shared device phase bodies ---------------------------------

__device__ inline void scan256(int* ss, int t) {
#pragma unroll
    for (int off = 1; off < 256; off <<= 1) {
        int u = (t >= off) ? ss[t - off] : 0;
        __syncthreads();
        ss[t] += u;
        __syncthreads();
    }
}

// phase A: hist | cvt_x | cvt_w | zero(pooled) | gstart
__global__ __launch_bounds__(256) void k_phase_a(
    const int* __restrict__ dst, int* __restrict__ bhist, int E,
    const float* __restrict__ x, unsigned short* __restrict__ xb,
    unsigned char* __restrict__ xf8, int nX,
    const float* __restrict__ Wl1, const float* __restrict__ Wr1,
    const float* __restrict__ Wl2, const float* __restrict__ Wr2,
    unsigned short* __restrict__ wbuf,
    float* __restrict__ pooled,
    const int* __restrict__ batch, int* __restrict__ gstart, int N, int G,
    int bHist, int bCvtX, int bCvtW, int bZero) {
    __shared__ int h[256];
    int b = blockIdx.x;
    int tid = threadIdx.x;
    if (b < bHist) {
        h[tid] = 0;
        __syncthreads();
        int e = b * EPB + tid * 4;
        if (e + 3 < E) {
            int4 d4 = *(const int4*)(dst + e);
            atomicAdd(&h[d4.x >> BSH], 1);
            atomicAdd(&h[d4.y >> BSH], 1);
            atomicAdd(&h[d4.z >> BSH], 1);
            atomicAdd(&h[d4.w >> BSH], 1);
        } else {
            for (int k = e; k < E; ++k) atomicAdd(&h[dst[k] >> BSH], 1);
        }
        __syncthreads();
        bhist[(size_t)b * 256 + tid] = h[tid];
    } else if (b < bHist + bCvtX) {
        int i = ((b - bHist) * 256 + tid) * 8;
        if (i < nX) {
            float4 v0 = *(const float4*)(x + i);
            float4 v1 = *(const float4*)(x + i + 4);
            uint4 ob;
            ob.x = pack2(v0.x, v0.y);
            ob.y = pack2(v0.z, v0.w);
            ob.z = pack2(v1.x, v1.y);
            ob.w = pack2(v1.z, v1.w);
            *(uint4*)(xb + i) = ob;
            uint2 of;
            of.x = enc4_fp8(v0.x, v0.y, v0.z, v0.w);
            of.y = enc4_fp8(v1.x, v1.y, v1.z, v1.w);
            *(uint2*)(xf8 + i) = of;
        }
    } else if (b < bHist + bCvtX + bCvtW) {
        int i = (b - bHist - bCvtX) * 256 + tid;
        if (i < 49152) {
            float v;
            if (i < 8192)       v = Wl1[i];
            else if (i < 16384) v = Wr1[i - 8192];
            else if (i < 32768) v = Wl2[i - 16384];
            else                v = Wr2[i - 32768];
            wbuf[i] = f2b(v);
        }
    } else if (b < bHist + bCvtX + bCvtW + bZero) {
        // zero pooled[256][128] (32768 floats) — consumed by linear2 atomics
        int i = ((b - bHist - bCvtX - bCvtW) * 256 + tid) * 4;
        float4 z = make_float4(0.f, 0.f, 0.f, 0.f);
        *(float4*)(pooled + i) = z;
    } else {
        for (int g = tid; g <= G; g += 256) {
            if (g == G) { gstart[G] = N; continue; }
            int lo = 0, hi = N;
            while (lo < hi) {
                int mid = (lo + hi) >> 1;
                if (batch[mid] < g) lo = mid + 1; else hi = mid;
            }
            gstart[g] = lo;
        }
    }
}

// column scan: for bucket k, exclusive-prefix bhist[:,k] over blocks; btot[k]=total
__global__ __launch_bounds__(256) void k_scan_bh(int* __restrict__ bhist,
                                                 int* __restrict__ btot, int nb) {
    __shared__ int ss[256];
    int k = blockIdx.x;
    int t = threadIdx.x;
    int b0 = t * 4;
    int v[4];
    int sum = 0;
#pragma unroll
    for (int i = 0; i < 4; ++i) {
        int b = b0 + i;
        v[i] = (b < nb) ? bhist[(size_t)b * 256 + k] : 0;
        sum += v[i];
    }
    ss[t] = sum;
    __syncthreads();
    scan256(ss, t);
    int run = ss[t] - sum;
#pragma unroll
    for (int i = 0; i < 4; ++i) {
        int b = b0 + i;
        if (b < nb) { bhist[(size_t)b * 256 + k] = run; run += v[i]; }
    }
    if (t == 0) btot[k] = ss[255];
}

// scatter edges into bucket-grouped ebuf; positions via LDS cursors.
// bucket bases recomputed locally from btot. record = (dst&511)<<23 | src
__global__ __launch_bounds__(256) void k_scatter_b(
    const int* __restrict__ src, const int* __restrict__ dst,
    const int* __restrict__ bhist, const int* __restrict__ btot,
    int* __restrict__ ebuf, int E) {
    __shared__ int ss[256];
    __shared__ int lbase[256];
    int b = blockIdx.x;
    int t = threadIdx.x;
    int v = btot[t];
    ss[t] = v;
    __syncthreads();
    scan256(ss, t);
    lbase[t] = (ss[t] - v) + bhist[(size_t)b * 256 + t];
    __syncthreads();
    int e = b * EPB + t * 4;
    if (e + 3 < E) {
        int4 d4 = *(const int4*)(dst + e);
        int4 s4 = *(const int4*)(src + e);
        int k, p;
        k = d4.x >> BSH; p = atomicAdd(&lbase[k], 1); ebuf[p] = ((d4.x & 511) << 23) | s4.x;
        k = d4.y >> BSH; p = atomicAdd(&lbase[k], 1); ebuf[p] = ((d4.y & 511) << 23) | s4.y;
        k = d4.z >> BSH; p = atomicAdd(&lbase[k], 1); ebuf[p] = ((d4.z & 511) << 23) | s4.z;
        k = d4.w >> BSH; p = atomicAdd(&lbase[k], 1); ebuf[p] = ((d4.w & 511) << 23) | s4.w;
    } else {
        for (int q = e; q < E; ++q) {
            int d = dst[q];
            int p = atomicAdd(&lbase[d >> BSH], 1);
            ebuf[p] = ((d & 511) << 23) | src[q];
        }
    }
}

// per-bucket counting sort: 512-bin LDS histogram + scan -> row_start + csr_src
__global__ __launch_bounds__(256) void k_bucket_csr(
    const int* __restrict__ ebuf, const int* __restrict__ btot,
    int* __restrict__ row_start, int* __restrict__ csr_src, int N, int NB) {
    __shared__ int ss[256];
    __shared__ int bbS[257];
    __shared__ int h2[512];
    int k = blockIdx.x;
    int t = threadIdx.x;
    int v = btot[t];
    ss[t] = v;
    __syncthreads();
    scan256(ss, t);
    bbS[t] = ss[t] - v;
    if (t == 255) bbS[256] = ss[255];
    __syncthreads();
    int s = bbS[k], e = bbS[k + 1];
    int node0 = k << BSH;
    int nn = N - node0; if (nn > 512) nn = 512;
    if (k == NB - 1 && t == 0) row_start[node0 + nn] = e;
    h2[t] = 0; h2[t + 256] = 0;
    __syncthreads();
    for (int i = s + t; i < e; i += 256)
        atomicAdd(&h2[((uint)ebuf[i]) >> 23], 1);
    __syncthreads();
    int a0 = h2[2 * t], a1 = h2[2 * t + 1];
    int ps = a0 + a1;
    ss[t] = ps;
    __syncthreads();
    scan256(ss, t);
    int base = ss[t] - ps;
    h2[2 * t] = base;
    h2[2 * t + 1] = base + a0;
    __syncthreads();
    int rs0 = h2[t];
    int rs1 = h2[t + 256];
    __syncthreads();
    if (t < nn)       row_start[node0 + t]       = s + rs0;
    if (t + 256 < nn) row_start[node0 + t + 256] = s + rs1;
    for (int i = s + t; i < e; i += 256) {
        int rec = ebuf[i];
        int j = ((uint)rec) >> 23;
        int pos = atomicAdd(&h2[j], 1);
        csr_src[s + pos] = rec & 0x7FFFFF;
    }
}

// ---------------- mean aggregation (fp8 in, bf16 out, fp32 accumulate) -------
// 1 node per 64-lane wave, no LDS, full occupancy: latency hidden by waves.

#define ACCF8(v)                                                        \
    { floatx2 f = __builtin_amdgcn_cvt_pk_f32_fp8((v).x, false);        \
      a[0] += f[0]; a[1] += f[1];                                       \
      f = __builtin_amdgcn_cvt_pk_f32_fp8((v).x, true);                 \
      a[2] += f[0]; a[3] += f[1];                                       \
      f = __builtin_amdgcn_cvt_pk_f32_fp8((v).y, false);                \
      a[4] += f[0]; a[5] += f[1];                                       \
      f = __builtin_amdgcn_cvt_pk_f32_fp8((v).y, true);                 \
      a[6] += f[0]; a[7] += f[1]; }

// K=64: row = 64 B fp8. 8 edge-slots x 8 lanes x uint2; 2-deep unroll.
__global__ void k_gather1(const unsigned char* __restrict__ xf8,
                          const int* __restrict__ row_start,
                          const int* __restrict__ csr_src,
                          unsigned short* __restrict__ agg, int n_nodes) {
    int tid = threadIdx.x;
    int node = blockIdx.x * 4 + (tid >> 6);
    if (node >= n_nodes) return;
    int lane = tid & 63;
    int grp = lane >> 3;
    int lp  = lane & 7;
    int s = row_start[node];
    int e = row_start[node + 1];
    float a[8];
#pragma unroll
    for (int q = 0; q < 8; ++q) a[q] = 0.f;
    int i = s + grp;
    for (; i + 8 < e; i += 16) {
        int u0 = csr_src[i];
        int u1 = csr_src[i + 8];
        uint2 v0 = *(const uint2*)(xf8 + (size_t)u0 * 64 + lp * 8);
        uint2 v1 = *(const uint2*)(xf8 + (size_t)u1 * 64 + lp * 8);
        ACCF8(v0);
        ACCF8(v1);
    }
    if (i < e) {
        int u0 = csr_src[i];
        uint2 v0 = *(const uint2*)(xf8 + (size_t)u0 * 64 + lp * 8);
        ACCF8(v0);
    }
#pragma unroll
    for (int q = 0; q < 8; ++q) {
        a[q] += __shfl_xor(a[q], 8);
        a[q] += __shfl_xor(a[q], 16);
        a[q] += __shfl_xor(a[q], 32);
    }
    if (grp == 0) {
        int d = e - s;
        float scale = (d > 0) ? (1.f / (float)d) : 1.f;
        uint4 o;
        o.x = pack2(a[0] * scale, a[1] * scale);
        o.y = pack2(a[2] * scale, a[3] * scale);
        o.z = pack2(a[4] * scale, a[5] * scale);
        o.w = pack2(a[6] * scale, a[7] * scale);
        *(uint4*)(agg + (size_t)node * 64 + lp * 8) = o;
    }
}

// K=128: row = 128 B fp8. 4 edge-slots x 16 lanes x uint2; 2-deep unroll.
__global__ void k_gather2(const unsigned char* __restrict__ h1f8,
                          const int* __restrict__ row_start,
                          const int* __restrict__ csr_src,
                          unsigned short* __restrict__ agg, int n_nodes) {
    int tid = threadIdx.x;
    int node = blockIdx.x * 4 + (tid >> 6);
    if (node >= n_nodes) return;
    int lane = tid & 63;
    int grp = lane >> 4;
    int lp  = lane & 15;
    int s = row_start[node];
    int e = row_start[node + 1];
    float a[8];
#pragma unroll
    for (int q = 0; q < 8; ++q) a[q] = 0.f;
    int i = s + grp;
    for (; i + 4 < e; i += 8) {
        int u0 = csr_src[i];
        int u1 = csr_src[i + 4];
        uint2 v0 = *(const uint2*)(h1f8 + (size_t)u0 * 128 + lp * 8);
        uint2 v1 = *(const uint2*)(h1f8 + (size_t)u1 * 128 + lp * 8);
        ACCF8(v0);
        ACCF8(v1);
    }
    if (i < e) {
        int u0 = csr_src[i];
        uint2 v0 = *(const uint2*)(h1f8 + (size_t)u0 * 128 + lp * 8);
        ACCF8(v0);
    }
#pragma unroll
    for (int q = 0; q < 8; ++q) {
        a[q] += __shfl_xor(a[q], 16);
        a[q] += __shfl_xor(a[q], 32);
    }
    if (grp == 0) {
        int d = e - s;
        float scale = (d > 0) ? (1.f / (float)d) : 1.f;
        uint4 o;
        o.x = pack2(a[0] * scale, a[1] * scale);
        o.y = pack2(a[2] * scale, a[3] * scale);
        o.z = pack2(a[4] * scale, a[5] * scale);
        o.w = pack2(a[6] * scale, a[7] * scale);
        *(uint4*)(agg + (size_t)node * 128 + lp * 8) = o;
    }
}

// ---------------- MFMA SAGE linear: relu(agg@Wl.T + bl + xin@Wr.T) ----------
// FULL-TILE staging: both 128xK operands resident in LDS, ONE barrier, then
// the whole K-loop is sync-free MFMA+ds_read. Rows padded to K+8 shorts so
// the 16-row ds_read_b128 fragment reads spread uniformly across banks.
// POOL=false: emit bf16 h + fp8 copy. POOL=true: R2-validated epilogue —
// per-thread running per-graph sums + atomicAdd into pooled[G][128].

template <int K, bool POOL>
__global__ __launch_bounds__(256) void k_linear_mfma(
    const unsigned short* __restrict__ aggA, const unsigned short* __restrict__ xinA,
    const unsigned short* __restrict__ Wlb,  const float* __restrict__ bl,
    const unsigned short* __restrict__ Wrb,  unsigned short* __restrict__ out,
    unsigned char* __restrict__ outf8,
    const int* __restrict__ batch, float* __restrict__ pooled, int n_nodes) {
    constexpr int NCH = (2 * K) / 32;
    constexpr int KP = K + 8;              // padded row (shorts); row = (K+8)*2 B
    constexpr int SLOTS = K / 8;           // uint4 slots per row
    __shared__ __align__(16) short As[2 * 128 * KP];  // K=64: 36.9KB, K=128: 69.6KB
    __shared__ int bb[128];

    int tid  = threadIdx.x;
    int lane = tid & 63;
    int wave = tid >> 6;
    int quad = lane >> 4;
    int lr   = lane & 15;
    int node0 = blockIdx.x * 128;

    if (POOL && tid < 128) {
        int n = node0 + tid;
        bb[tid] = (n < n_nodes) ? batch[n] : 0;
    }

    // ---- stage both full tiles, all loads in flight, one barrier ------------
#pragma unroll
    for (int idx = tid; idx < 128 * SLOTS; idx += 256) {
        int row  = idx / SLOTS;
        int slot = idx % SLOTS;
        int n = node0 + row; if (n >= n_nodes) n = n_nodes - 1;
        uint4 va = *(const uint4*)(aggA + (size_t)n * K + slot * 8);
        uint4 vx = *(const uint4*)(xinA + (size_t)n * K + slot * 8);
        *(uint4*)(&As[row * KP + slot * 8]) = va;
        *(uint4*)(&As[128 * KP + row * KP + slot * 8]) = vx;
    }
    __syncthreads();

    floatx4 acc[8][2];
#pragma unroll
    for (int mi = 0; mi < 8; ++mi)
#pragma unroll
        for (int ni = 0; ni < 2; ++ni)
            acc[mi][ni] = (floatx4){0.f, 0.f, 0.f, 0.f};

#pragma unroll
    for (int c = 0; c < NCH; ++c) {
        const unsigned short* srcW = (c < K / 32) ? Wlb : Wrb;
        int base = (c < K / 32) ? 0 : 128 * KP;
        int kb   = (c < K / 32) ? c * 32 : (c - K / 32) * 32;

        short8_t bfrag[2];
#pragma unroll
        for (int ni = 0; ni < 2; ++ni) {
            int j = wave * 32 + ni * 16 + lr;
            bfrag[ni] = *(const short8_t*)(srcW + (size_t)j * K + kb + quad * 8);
        }
#pragma unroll
        for (int mi = 0; mi < 8; ++mi) {
            short8_t af = *(const short8_t*)(&As[base + (mi * 16 + lr) * KP + kb + quad * 8]);
            acc[mi][0] = __builtin_amdgcn_mfma_f32_16x16x32_bf16(af, bfrag[0], acc[mi][0], 0, 0, 0);
            acc[mi][1] = __builtin_amdgcn_mfma_f32_16x16x32_bf16(af, bfrag[1], acc[mi][1], 0, 0, 0);
        }
    }

    float b0 = bl[wave * 32 + lr];
    float b1 = bl[wave * 32 + 16 + lr];
    int j0 = wave * 32 + lr;

    if (!POOL) {
#pragma unroll
        for (int mi = 0; mi < 8; ++mi) {
#pragma unroll
            for (int r = 0; r < 4; ++r) {
                int node = node0 + mi * 16 + quad * 4 + r;
                if (node < n_nodes) {
                    float v0 = fmaxf(acc[mi][0][r] + b0, 0.f);
                    float v1 = fmaxf(acc[mi][1][r] + b1, 0.f);
                    out[(size_t)node * 128 + j0]      = f2b(v0);
                    out[(size_t)node * 128 + j0 + 16] = f2b(v1);
                    outf8[(size_t)node * 128 + j0]      = enc1_fp8(v0);
                    outf8[(size_t)node * 128 + j0 + 16] = enc1_fp8(v1);
                }
            }
        }
    } else {
        // R2-validated: thread's nodes are monotone -> running per-graph sums,
        // flush on boundary; ~1-2 graphs per 128-node window (batch sorted).
        int gcur = -1;
        float s0 = 0.f, s1 = 0.f;
#pragma unroll
        for (int mi = 0; mi < 8; ++mi) {
#pragma unroll
            for (int r = 0; r < 4; ++r) {
                int li = mi * 16 + quad * 4 + r;
                int node = node0 + li;
                if (node < n_nodes) {
                    float v0 = fmaxf(acc[mi][0][r] + b0, 0.f);
                    float v1 = fmaxf(acc[mi][1][r] + b1, 0.f);
                    int g = bb[li];
                    if (g != gcur) {
                        if (gcur >= 0) {
                            atomicAdd(&pooled[gcur * 128 + j0], s0);
                            atomicAdd(&pooled[gcur * 128 + j0 + 16], s1);
                        }
                        gcur = g; s0 = 0.f; s1 = 0.f;
                    }
                    s0 += v0;
                    s1 += v1;
                }
            }
        }
        if (gcur >= 0) {
            atomicAdd(&pooled[gcur * 128 + j0], s0);
            atomicAdd(&pooled[gcur * 128 + j0 + 16], s1);
        }
    }
}

// ---------------- tiny head: mean + linear + log_softmax ---------------------

__global__ void k_head(const float* __restrict__ pooled,
                       const int* __restrict__ gstart,
                       const float* __restrict__ Wout,
                       const float* __restrict__ bout,
                       float* __restrict__ out) {
    int g = blockIdx.x;
    int lane = threadIdx.x;  // 64
    float p0 = pooled[g * 128 + lane];
    float p1 = pooled[g * 128 + 64 + lane];
    float d0 = p0 * Wout[lane] + p1 * Wout[64 + lane];
    float d1 = p0 * Wout[128 + lane] + p1 * Wout[192 + lane];
#pragma unroll
    for (int m = 32; m > 0; m >>= 1) {
        d0 += __shfl_xor(d0, m);
        d1 += __shfl_xor(d1, m);
    }
    if (lane == 0) {
        float cnt = (float)(gstart[g + 1] - gstart[g]);
        float inv = (cnt > 0.f) ? (1.f / cnt) : 1.f;
        float l0 = d0 * inv + bout[0];
        float l1 = d1 * inv + bout[1];
        float mx = fmaxf(l0, l1);
        float lse = mx + logf(expf(l0 - mx) + expf(l1 - mx));
        out[g * 2 + 0] = l0 - lse;
        out[g * 2 + 1] = l1 - lse;
    }
}

// ---------------- launch -----------------------------------------------------

static inline size_t alignUp(size_t x, size_t a) { return (x + a - 1) & ~(a - 1); }

extern "C" void kernel_launch(void* const* d_in, const int* in_sizes, int n_in,
                              void* d_out, int out_size, void* d_ws, size_t ws_size,
                              hipStream_t stream) {
    const float* x    = (const float*)d_in[0];
    const int*   ei   = (const int*)d_in[1];
    const int*   batch= (const int*)d_in[2];
    const float* Wl1  = (const float*)d_in[3];
    const float* bl1  = (const float*)d_in[4];
    const float* Wr1  = (const float*)d_in[5];
    const float* Wl2  = (const float*)d_in[6];
    const float* bl2  = (const float*)d_in[7];
    const float* Wr2  = (const float*)d_in[8];
    const float* Wout = (const float*)d_in[9];
    const float* bout = (const float*)d_in[10];
    float* out = (float*)d_out;

    const int N = in_sizes[0] / 64;   // 100000 (must be < 2^23 for record packing)
    const int E = in_sizes[1] / 2;    // 1000000
    const int G = out_size / 2;       // 256

    const int* src = ei;
    const int* dst = ei + E;

    const int bHist = (E + EPB - 1) / EPB;     // 977
    const int NB    = (N + 511) >> BSH;        // 196 coarse buckets
    const int bCvtX = (N * 64 / 8 + 255) / 256;
    const int bCvtW = 192;
    const int bZero = (G * 128 / 4 + 255) / 256;    // 32
    const int NV1   = (N + 3) / 4;

    // workspace layout
    char* ws = (char*)d_ws;
    size_t off = 0;
    int*   bhist     = (int*)(ws + off); off = alignUp(off + (size_t)bHist * 256 * 4, 256);
    int*   btot      = (int*)(ws + off); off = alignUp(off + (size_t)257 * 4, 256);
    int*   row_start = (int*)(ws + off); off = alignUp(off + (size_t)(N + 1) * 4, 256);
    int*   ebuf      = (int*)(ws + off); off = alignUp(off + (size_t)E * 4, 256);
    int*   csr_src   = (int*)(ws + off); off = alignUp(off + (size_t)E * 4, 256);
    int*   gstart    = (int*)(ws + off); off = alignUp(off + (size_t)(G + 1) * 4, 256);
    unsigned short* xb   = (unsigned short*)(ws + off); off = alignUp(off + (size_t)N * 64 * 2, 256);
    unsigned char*  xf8  = (unsigned char*)(ws + off);  off = alignUp(off + (size_t)N * 64, 256);
    unsigned short* wbuf = (unsigned short*)(ws + off); off = alignUp(off + (size_t)49152 * 2, 256);
    unsigned short* agg1 = (unsigned short*)(ws + off); off = alignUp(off + (size_t)N * 64 * 2, 256);
    unsigned short* h1   = (unsigned short*)(ws + off); off = alignUp(off + (size_t)N * 128 * 2, 256);
    unsigned char*  h1f8 = (unsigned char*)(ws + off);  off = alignUp(off + (size_t)N * 128, 256);
    unsigned short* agg2 = (unsigned short*)(ws + off); off = alignUp(off + (size_t)N * 128 * 2, 256);
    float*          pooled = (float*)(ws + off); off = alignUp(off + (size_t)G * 128 * 4, 256);
    (void)ws_size;

    unsigned short* Wl1b = wbuf;
    unsigned short* Wr1b = wbuf + 8192;
    unsigned short* Wl2b = wbuf + 16384;
    unsigned short* Wr2b = wbuf + 32768;

    // phase A: LDS bucket histogram + cvt_x + cvt_w + zero(pooled) + graph bounds
    k_phase_a<<<bHist + bCvtX + bCvtW + bZero + 1, 256, 0, stream>>>(
        dst, bhist, E,
        x, xb, xf8, N * 64,
        Wl1, Wr1, Wl2, Wr2, wbuf,
        pooled,
        batch, gstart, N, G,
        bHist, bCvtX, bCvtW, bZero);

    // bucket scans + bucket-grouped scatter + per-bucket counting sort
    k_scan_bh<<<256, 256, 0, stream>>>(bhist, btot, bHist);
    k_scatter_b<<<bHist, 256, 0, stream>>>(src, dst, bhist, btot, ebuf, E);
    k_bucket_csr<<<NB, 256, 0, stream>>>(ebuf, btot, row_start, csr_src, N, NB);

    // layer 1: gather (fp8) -> MFMA linear (emits h1 bf16 + h1f8 fp8)
    k_gather1<<<NV1, 256, 0, stream>>>(xf8, row_start, csr_src, agg1, N);
    k_linear_mfma<64, false><<<(N + 127) / 128, 256, 0, stream>>>(
        agg1, xb, Wl1b, bl1, Wr1b, h1, h1f8, nullptr, nullptr, N);

    // layer 2: gather -> MFMA linear + per-graph pool (fp32 atomics)
    k_gather2<<<NV1, 256, 0, stream>>>(h1f8, row_start, csr_src, agg2, N);
    k_linear_mfma<128, true><<<(N + 127) / 128, 256, 0, stream>>>(
        agg2, h1, Wl2b, bl2, Wr2b, nullptr, nullptr, batch, pooled, N);

    // tiny head: mean + 128->2 linear + log_softmax
    k_head<<<G, 64, 0, stream>>>(pooled, gstart, Wout, bout, out);
}

// Round 6
// 230.429 us; speedup vs baseline: 5.6085x; 1.1107x over previous
//
#include <hip/hip_runtime.h>
#include <hip/hip_bf16.h>
#include <math.h>

typedef short short8_t __attribute__((ext_vector_type(8)));
typedef float floatx4  __attribute__((ext_vector_type(4)));
typedef float floatx2  __attribute__((ext_vector_type(2)));
typedef unsigned int uint;

#define EPB 1024   // edges per histogram/scatter block
#define BSH 9      // 512 nodes per coarse bucket

// ---------------- bf16 helpers (RNE) ----------------------------------------

__device__ inline unsigned short f2b(float f) {
    uint u = __float_as_uint(f);
    u += 0x7fff + ((u >> 16) & 1);
    return (unsigned short)(u >> 16);
}
__device__ inline uint pack2(float a, float b) {
    return (uint)f2b(a) | ((uint)f2b(b) << 16);
}

// ---------------- fp8 (e4m3) helpers -----------------------------------------

__device__ inline uint enc4_fp8(float f0, float f1, float f2, float f3) {
    uint v = __builtin_amdgcn_cvt_pk_fp8_f32(f0, f1, 0, false);
    v = __builtin_amdgcn_cvt_pk_fp8_f32(f2, f3, v, true);
    return v;
}
__device__ inline unsigned char enc1_fp8(float f) {
    return (unsigned char)(__builtin_amdgcn_cvt_pk_fp8_f32(f, f, 0, false) & 0xff);
}

// Lesson ledger:
//  R10/R13: GLOBAL atomic histogram pinned ~43-50us — replaced by LDS hist.
//  R12: co-scheduling light branches in one grid is free.
//  R11/R14/R15: a latency-bound phase inherits a fused kernel's worst-phase
//       occupancy — per-BLOCK fusion of gather into MFMA collapsed (139us).
//  R9: keep scatter targets packed (L2-resident).
//  R16: split structure, 9 dispatches -> 258us.
//  R17 (FAILED): coop grid.sync costs ~350us EACH on 8-XCD gfx950. Never.
//  R18 (FAILED): device-scope fences/tickets per block are mini grid.syncs.
//  R19: full-tile single-barrier linear staging — neutral (255.9us). Counters
//       finally exposed k_gather2: 40us, HBM 25%, VALU 55% — NOT BW-bound;
//       per-node overhead (16 shfl reduce + 48-lane-idle epilogue) dominates
//       at mean degree 10.
//  R20 (this round): gathers restructured to 1 node per 16-lane (K=128) /
//       8-lane (K=64) group, 4/8 nodes per wave: no cross-lane reduce, fully
//       lane-parallel epilogue, serial edge loop w/ 2-deep unroll. Divergence
//       (max-degree among groups) is the cheap price.

// ---------------- shared device phase bodies ---------------------------------

__device__ inline void scan256(int* ss, int t) {
#pragma unroll
    for (int off = 1; off < 256; off <<= 1) {
        int u = (t >= off) ? ss[t - off] : 0;
        __syncthreads();
        ss[t] += u;
        __syncthreads();
    }
}

// phase A: hist | cvt_x | cvt_w | zero(pooled) | gstart
__global__ __launch_bounds__(256) void k_phase_a(
    const int* __restrict__ dst, int* __restrict__ bhist, int E,
    const float* __restrict__ x, unsigned short* __restrict__ xb,
    unsigned char* __restrict__ xf8, int nX,
    const float* __restrict__ Wl1, const float* __restrict__ Wr1,
    const float* __restrict__ Wl2, const float* __restrict__ Wr2,
    unsigned short* __restrict__ wbuf,
    float* __restrict__ pooled,
    const int* __restrict__ batch, int* __restrict__ gstart, int N, int G,
    int bHist, int bCvtX, int bCvtW, int bZero) {
    __shared__ int h[256];
    int b = blockIdx.x;
    int tid = threadIdx.x;
    if (b < bHist) {
        h[tid] = 0;
        __syncthreads();
        int e = b * EPB + tid * 4;
        if (e + 3 < E) {
            int4 d4 = *(const int4*)(dst + e);
            atomicAdd(&h[d4.x >> BSH], 1);
            atomicAdd(&h[d4.y >> BSH], 1);
            atomicAdd(&h[d4.z >> BSH], 1);
            atomicAdd(&h[d4.w >> BSH], 1);
        } else {
            for (int k = e; k < E; ++k) atomicAdd(&h[dst[k] >> BSH], 1);
        }
        __syncthreads();
        bhist[(size_t)b * 256 + tid] = h[tid];
    } else if (b < bHist + bCvtX) {
        int i = ((b - bHist) * 256 + tid) * 8;
        if (i < nX) {
            float4 v0 = *(const float4*)(x + i);
            float4 v1 = *(const float4*)(x + i + 4);
            uint4 ob;
            ob.x = pack2(v0.x, v0.y);
            ob.y = pack2(v0.z, v0.w);
            ob.z = pack2(v1.x, v1.y);
            ob.w = pack2(v1.z, v1.w);
            *(uint4*)(xb + i) = ob;
            uint2 of;
            of.x = enc4_fp8(v0.x, v0.y, v0.z, v0.w);
            of.y = enc4_fp8(v1.x, v1.y, v1.z, v1.w);
            *(uint2*)(xf8 + i) = of;
        }
    } else if (b < bHist + bCvtX + bCvtW) {
        int i = (b - bHist - bCvtX) * 256 + tid;
        if (i < 49152) {
            float v;
            if (i < 8192)       v = Wl1[i];
            else if (i < 16384) v = Wr1[i - 8192];
            else if (i < 32768) v = Wl2[i - 16384];
            else                v = Wr2[i - 32768];
            wbuf[i] = f2b(v);
        }
    } else if (b < bHist + bCvtX + bCvtW + bZero) {
        // zero pooled[256][128] (32768 floats) — consumed by linear2 atomics
        int i = ((b - bHist - bCvtX - bCvtW) * 256 + tid) * 4;
        float4 z = make_float4(0.f, 0.f, 0.f, 0.f);
        *(float4*)(pooled + i) = z;
    } else {
        for (int g = tid; g <= G; g += 256) {
            if (g == G) { gstart[G] = N; continue; }
            int lo = 0, hi = N;
            while (lo < hi) {
                int mid = (lo + hi) >> 1;
                if (batch[mid] < g) lo = mid + 1; else hi = mid;
            }
            gstart[g] = lo;
        }
    }
}

// column scan: for bucket k, exclusive-prefix bhist[:,k] over blocks; btot[k]=total
__global__ __launch_bounds__(256) void k_scan_bh(int* __restrict__ bhist,
                                                 int* __restrict__ btot, int nb) {
    __shared__ int ss[256];
    int k = blockIdx.x;
    int t = threadIdx.x;
    int b0 = t * 4;
    int v[4];
    int sum = 0;
#pragma unroll
    for (int i = 0; i < 4; ++i) {
        int b = b0 + i;
        v[i] = (b < nb) ? bhist[(size_t)b * 256 + k] : 0;
        sum += v[i];
    }
    ss[t] = sum;
    __syncthreads();
    scan256(ss, t);
    int run = ss[t] - sum;
#pragma unroll
    for (int i = 0; i < 4; ++i) {
        int b = b0 + i;
        if (b < nb) { bhist[(size_t)b * 256 + k] = run; run += v[i]; }
    }
    if (t == 0) btot[k] = ss[255];
}

// scatter edges into bucket-grouped ebuf; positions via LDS cursors.
// bucket bases recomputed locally from btot. record = (dst&511)<<23 | src
__global__ __launch_bounds__(256) void k_scatter_b(
    const int* __restrict__ src, const int* __restrict__ dst,
    const int* __restrict__ bhist, const int* __restrict__ btot,
    int* __restrict__ ebuf, int E) {
    __shared__ int ss[256];
    __shared__ int lbase[256];
    int b = blockIdx.x;
    int t = threadIdx.x;
    int v = btot[t];
    ss[t] = v;
    __syncthreads();
    scan256(ss, t);
    lbase[t] = (ss[t] - v) + bhist[(size_t)b * 256 + t];
    __syncthreads();
    int e = b * EPB + t * 4;
    if (e + 3 < E) {
        int4 d4 = *(const int4*)(dst + e);
        int4 s4 = *(const int4*)(src + e);
        int k, p;
        k = d4.x >> BSH; p = atomicAdd(&lbase[k], 1); ebuf[p] = ((d4.x & 511) << 23) | s4.x;
        k = d4.y >> BSH; p = atomicAdd(&lbase[k], 1); ebuf[p] = ((d4.y & 511) << 23) | s4.y;
        k = d4.z >> BSH; p = atomicAdd(&lbase[k], 1); ebuf[p] = ((d4.z & 511) << 23) | s4.z;
        k = d4.w >> BSH; p = atomicAdd(&lbase[k], 1); ebuf[p] = ((d4.w & 511) << 23) | s4.w;
    } else {
        for (int q = e; q < E; ++q) {
            int d = dst[q];
            int p = atomicAdd(&lbase[d >> BSH], 1);
            ebuf[p] = ((d & 511) << 23) | src[q];
        }
    }
}

// per-bucket counting sort: 512-bin LDS histogram + scan -> row_start + csr_src
__global__ __launch_bounds__(256) void k_bucket_csr(
    const int* __restrict__ ebuf, const int* __restrict__ btot,
    int* __restrict__ row_start, int* __restrict__ csr_src, int N, int NB) {
    __shared__ int ss[256];
    __shared__ int bbS[257];
    __shared__ int h2[512];
    int k = blockIdx.x;
    int t = threadIdx.x;
    int v = btot[t];
    ss[t] = v;
    __syncthreads();
    scan256(ss, t);
    bbS[t] = ss[t] - v;
    if (t == 255) bbS[256] = ss[255];
    __syncthreads();
    int s = bbS[k], e = bbS[k + 1];
    int node0 = k << BSH;
    int nn = N - node0; if (nn > 512) nn = 512;
    if (k == NB - 1 && t == 0) row_start[node0 + nn] = e;
    h2[t] = 0; h2[t + 256] = 0;
    __syncthreads();
    for (int i = s + t; i < e; i += 256)
        atomicAdd(&h2[((uint)ebuf[i]) >> 23], 1);
    __syncthreads();
    int a0 = h2[2 * t], a1 = h2[2 * t + 1];
    int ps = a0 + a1;
    ss[t] = ps;
    __syncthreads();
    scan256(ss, t);
    int base = ss[t] - ps;
    h2[2 * t] = base;
    h2[2 * t + 1] = base + a0;
    __syncthreads();
    int rs0 = h2[t];
    int rs1 = h2[t + 256];
    __syncthreads();
    if (t < nn)       row_start[node0 + t]       = s + rs0;
    if (t + 256 < nn) row_start[node0 + t + 256] = s + rs1;
    for (int i = s + t; i < e; i += 256) {
        int rec = ebuf[i];
        int j = ((uint)rec) >> 23;
        int pos = atomicAdd(&h2[j], 1);
        csr_src[s + pos] = rec & 0x7FFFFF;
    }
}

// ---------------- mean aggregation (fp8 in, bf16 out, fp32 accumulate) -------
// R20: 1 node per LANE-GROUP (not per wave): no cross-lane reduce, every lane
// packs/stores its own 8 outputs. Serial edge loop, 2-deep unroll for MLP.

#define ACCF8(v)                                                        \
    { floatx2 f = __builtin_amdgcn_cvt_pk_f32_fp8((v).x, false);        \
      a[0] += f[0]; a[1] += f[1];                                       \
      f = __builtin_amdgcn_cvt_pk_f32_fp8((v).x, true);                 \
      a[2] += f[0]; a[3] += f[1];                                       \
      f = __builtin_amdgcn_cvt_pk_f32_fp8((v).y, false);                \
      a[4] += f[0]; a[5] += f[1];                                       \
      f = __builtin_amdgcn_cvt_pk_f32_fp8((v).y, true);                 \
      a[6] += f[0]; a[7] += f[1]; }

// K=64: 8 lanes per node (8B each), 32 nodes per 256-thread block.
__global__ void k_gather1(const unsigned char* __restrict__ xf8,
                          const int* __restrict__ row_start,
                          const int* __restrict__ csr_src,
                          unsigned short* __restrict__ agg, int n_nodes) {
    int tid = threadIdx.x;
    int node = blockIdx.x * 32 + (tid >> 3);
    if (node >= n_nodes) return;
    int lp = tid & 7;
    int s = row_start[node];
    int e = row_start[node + 1];
    float a[8];
#pragma unroll
    for (int q = 0; q < 8; ++q) a[q] = 0.f;
    int i = s;
    for (; i + 1 < e; i += 2) {
        int u0 = csr_src[i];
        int u1 = csr_src[i + 1];
        uint2 v0 = *(const uint2*)(xf8 + (size_t)u0 * 64 + lp * 8);
        uint2 v1 = *(const uint2*)(xf8 + (size_t)u1 * 64 + lp * 8);
        ACCF8(v0);
        ACCF8(v1);
    }
    if (i < e) {
        int u0 = csr_src[i];
        uint2 v0 = *(const uint2*)(xf8 + (size_t)u0 * 64 + lp * 8);
        ACCF8(v0);
    }
    int d = e - s;
    float scale = (d > 0) ? (1.f / (float)d) : 1.f;
    uint4 o;
    o.x = pack2(a[0] * scale, a[1] * scale);
    o.y = pack2(a[2] * scale, a[3] * scale);
    o.z = pack2(a[4] * scale, a[5] * scale);
    o.w = pack2(a[6] * scale, a[7] * scale);
    *(uint4*)(agg + (size_t)node * 64 + lp * 8) = o;
}

// K=128: 16 lanes per node (8B each), 16 nodes per 256-thread block.
__global__ void k_gather2(const unsigned char* __restrict__ h1f8,
                          const int* __restrict__ row_start,
                          const int* __restrict__ csr_src,
                          unsigned short* __restrict__ agg, int n_nodes) {
    int tid = threadIdx.x;
    int node = blockIdx.x * 16 + (tid >> 4);
    if (node >= n_nodes) return;
    int lp = tid & 15;
    int s = row_start[node];
    int e = row_start[node + 1];
    float a[8];
#pragma unroll
    for (int q = 0; q < 8; ++q) a[q] = 0.f;
    int i = s;
    for (; i + 1 < e; i += 2) {
        int u0 = csr_src[i];
        int u1 = csr_src[i + 1];
        uint2 v0 = *(const uint2*)(h1f8 + (size_t)u0 * 128 + lp * 8);
        uint2 v1 = *(const uint2*)(h1f8 + (size_t)u1 * 128 + lp * 8);
        ACCF8(v0);
        ACCF8(v1);
    }
    if (i < e) {
        int u0 = csr_src[i];
        uint2 v0 = *(const uint2*)(h1f8 + (size_t)u0 * 128 + lp * 8);
        ACCF8(v0);
    }
    int d = e - s;
    float scale = (d > 0) ? (1.f / (float)d) : 1.f;
    uint4 o;
    o.x = pack2(a[0] * scale, a[1] * scale);
    o.y = pack2(a[2] * scale, a[3] * scale);
    o.z = pack2(a[4] * scale, a[5] * scale);
    o.w = pack2(a[6] * scale, a[7] * scale);
    *(uint4*)(agg + (size_t)node * 128 + lp * 8) = o;
}

// ---------------- MFMA SAGE linear: relu(agg@Wl.T + bl + xin@Wr.T) ----------
// FULL-TILE staging: both 128xK operands resident in LDS, ONE barrier, then
// the whole K-loop is sync-free MFMA+ds_read. Rows padded to K+8 shorts.
// POOL=false: emit bf16 h + fp8 copy. POOL=true: R2-validated epilogue —
// per-thread running per-graph sums + atomicAdd into pooled[G][128].

template <int K, bool POOL>
__global__ __launch_bounds__(256) void k_linear_mfma(
    const unsigned short* __restrict__ aggA, const unsigned short* __restrict__ xinA,
    const unsigned short* __restrict__ Wlb,  const float* __restrict__ bl,
    const unsigned short* __restrict__ Wrb,  unsigned short* __restrict__ out,
    unsigned char* __restrict__ outf8,
    const int* __restrict__ batch, float* __restrict__ pooled, int n_nodes) {
    constexpr int NCH = (2 * K) / 32;
    constexpr int KP = K + 8;              // padded row (shorts)
    constexpr int SLOTS = K / 8;           // uint4 slots per row
    __shared__ __align__(16) short As[2 * 128 * KP];
    __shared__ int bb[128];

    int tid  = threadIdx.x;
    int lane = tid & 63;
    int wave = tid >> 6;
    int quad = lane >> 4;
    int lr   = lane & 15;
    int node0 = blockIdx.x * 128;

    if (POOL && tid < 128) {
        int n = node0 + tid;
        bb[tid] = (n < n_nodes) ? batch[n] : 0;
    }

    // ---- stage both full tiles, all loads in flight, one barrier ------------
#pragma unroll
    for (int idx = tid; idx < 128 * SLOTS; idx += 256) {
        int row  = idx / SLOTS;
        int slot = idx % SLOTS;
        int n = node0 + row; if (n >= n_nodes) n = n_nodes - 1;
        uint4 va = *(const uint4*)(aggA + (size_t)n * K + slot * 8);
        uint4 vx = *(const uint4*)(xinA + (size_t)n * K + slot * 8);
        *(uint4*)(&As[row * KP + slot * 8]) = va;
        *(uint4*)(&As[128 * KP + row * KP + slot * 8]) = vx;
    }
    __syncthreads();

    floatx4 acc[8][2];
#pragma unroll
    for (int mi = 0; mi < 8; ++mi)
#pragma unroll
        for (int ni = 0; ni < 2; ++ni)
            acc[mi][ni] = (floatx4){0.f, 0.f, 0.f, 0.f};

#pragma unroll
    for (int c = 0; c < NCH; ++c) {
        const unsigned short* srcW = (c < K / 32) ? Wlb : Wrb;
        int base = (c < K / 32) ? 0 : 128 * KP;
        int kb   = (c < K / 32) ? c * 32 : (c - K / 32) * 32;

        short8_t bfrag[2];
#pragma unroll
        for (int ni = 0; ni < 2; ++ni) {
            int j = wave * 32 + ni * 16 + lr;
            bfrag[ni] = *(const short8_t*)(srcW + (size_t)j * K + kb + quad * 8);
        }
#pragma unroll
        for (int mi = 0; mi < 8; ++mi) {
            short8_t af = *(const short8_t*)(&As[base + (mi * 16 + lr) * KP + kb + quad * 8]);
            acc[mi][0] = __builtin_amdgcn_mfma_f32_16x16x32_bf16(af, bfrag[0], acc[mi][0], 0, 0, 0);
            acc[mi][1] = __builtin_amdgcn_mfma_f32_16x16x32_bf16(af, bfrag[1], acc[mi][1], 0, 0, 0);
        }
    }

    float b0 = bl[wave * 32 + lr];
    float b1 = bl[wave * 32 + 16 + lr];
    int j0 = wave * 32 + lr;

    if (!POOL) {
#pragma unroll
        for (int mi = 0; mi < 8; ++mi) {
#pragma unroll
            for (int r = 0; r < 4; ++r) {
                int node = node0 + mi * 16 + quad * 4 + r;
                if (node < n_nodes) {
                    float v0 = fmaxf(acc[mi][0][r] + b0, 0.f);
                    float v1 = fmaxf(acc[mi][1][r] + b1, 0.f);
                    out[(size_t)node * 128 + j0]      = f2b(v0);
                    out[(size_t)node * 128 + j0 + 16] = f2b(v1);
                    outf8[(size_t)node * 128 + j0]      = enc1_fp8(v0);
                    outf8[(size_t)node * 128 + j0 + 16] = enc1_fp8(v1);
                }
            }
        }
    } else {
        // R2-validated: thread's nodes are monotone -> running per-graph sums,
        // flush on boundary; ~1-2 graphs per 128-node window (batch sorted).
        int gcur = -1;
        float s0 = 0.f, s1 = 0.f;
#pragma unroll
        for (int mi = 0; mi < 8; ++mi) {
#pragma unroll
            for (int r = 0; r < 4; ++r) {
                int li = mi * 16 + quad * 4 + r;
                int node = node0 + li;
                if (node < n_nodes) {
                    float v0 = fmaxf(acc[mi][0][r] + b0, 0.f);
                    float v1 = fmaxf(acc[mi][1][r] + b1, 0.f);
                    int g = bb[li];
                    if (g != gcur) {
                        if (gcur >= 0) {
                            atomicAdd(&pooled[gcur * 128 + j0], s0);
                            atomicAdd(&pooled[gcur * 128 + j0 + 16], s1);
                        }
                        gcur = g; s0 = 0.f; s1 = 0.f;
                    }
                    s0 += v0;
                    s1 += v1;
                }
            }
        }
        if (gcur >= 0) {
            atomicAdd(&pooled[gcur * 128 + j0], s0);
            atomicAdd(&pooled[gcur * 128 + j0 + 16], s1);
        }
    }
}

// ---------------- tiny head: mean + linear + log_softmax ---------------------

__global__ void k_head(const float* __restrict__ pooled,
                       const int* __restrict__ gstart,
                       const float* __restrict__ Wout,
                       const float* __restrict__ bout,
                       float* __restrict__ out) {
    int g = blockIdx.x;
    int lane = threadIdx.x;  // 64
    float p0 = pooled[g * 128 + lane];
    float p1 = pooled[g * 128 + 64 + lane];
    float d0 = p0 * Wout[lane] + p1 * Wout[64 + lane];
    float d1 = p0 * Wout[128 + lane] + p1 * Wout[192 + lane];
#pragma unroll
    for (int m = 32; m > 0; m >>= 1) {
        d0 += __shfl_xor(d0, m);
        d1 += __shfl_xor(d1, m);
    }
    if (lane == 0) {
        float cnt = (float)(gstart[g + 1] - gstart[g]);
        float inv = (cnt > 0.f) ? (1.f / cnt) : 1.f;
        float l0 = d0 * inv + bout[0];
        float l1 = d1 * inv + bout[1];
        float mx = fmaxf(l0, l1);
        float lse = mx + logf(expf(l0 - mx) + expf(l1 - mx));
        out[g * 2 + 0] = l0 - lse;
        out[g * 2 + 1] = l1 - lse;
    }
}

// ---------------- launch -----------------------------------------------------

static inline size_t alignUp(size_t x, size_t a) { return (x + a - 1) & ~(a - 1); }

extern "C" void kernel_launch(void* const* d_in, const int* in_sizes, int n_in,
                              void* d_out, int out_size, void* d_ws, size_t ws_size,
                              hipStream_t stream) {
    const float* x    = (const float*)d_in[0];
    const int*   ei   = (const int*)d_in[1];
    const int*   batch= (const int*)d_in[2];
    const float* Wl1  = (const float*)d_in[3];
    const float* bl1  = (const float*)d_in[4];
    const float* Wr1  = (const float*)d_in[5];
    const float* Wl2  = (const float*)d_in[6];
    const float* bl2  = (const float*)d_in[7];
    const float* Wr2  = (const float*)d_in[8];
    const float* Wout = (const float*)d_in[9];
    const float* bout = (const float*)d_in[10];
    float* out = (float*)d_out;

    const int N = in_sizes[0] / 64;   // 100000 (must be < 2^23 for record packing)
    const int E = in_sizes[1] / 2;    // 1000000
    const int G = out_size / 2;       // 256

    const int* src = ei;
    const int* dst = ei + E;

    const int bHist = (E + EPB - 1) / EPB;     // 977
    const int NB    = (N + 511) >> BSH;        // 196 coarse buckets
    const int bCvtX = (N * 64 / 8 + 255) / 256;
    const int bCvtW = 192;
    const int bZero = (G * 128 / 4 + 255) / 256;    // 32

    // workspace layout
    char* ws = (char*)d_ws;
    size_t off = 0;
    int*   bhist     = (int*)(ws + off); off = alignUp(off + (size_t)bHist * 256 * 4, 256);
    int*   btot      = (int*)(ws + off); off = alignUp(off + (size_t)257 * 4, 256);
    int*   row_start = (int*)(ws + off); off = alignUp(off + (size_t)(N + 1) * 4, 256);
    int*   ebuf      = (int*)(ws + off); off = alignUp(off + (size_t)E * 4, 256);
    int*   csr_src   = (int*)(ws + off); off = alignUp(off + (size_t)E * 4, 256);
    int*   gstart    = (int*)(ws + off); off = alignUp(off + (size_t)(G + 1) * 4, 256);
    unsigned short* xb   = (unsigned short*)(ws + off); off = alignUp(off + (size_t)N * 64 * 2, 256);
    unsigned char*  xf8  = (unsigned char*)(ws + off);  off = alignUp(off + (size_t)N * 64, 256);
    unsigned short* wbuf = (unsigned short*)(ws + off); off = alignUp(off + (size_t)49152 * 2, 256);
    unsigned short* agg1 = (unsigned short*)(ws + off); off = alignUp(off + (size_t)N * 64 * 2, 256);
    unsigned short* h1   = (unsigned short*)(ws + off); off = alignUp(off + (size_t)N * 128 * 2, 256);
    unsigned char*  h1f8 = (unsigned char*)(ws + off);  off = alignUp(off + (size_t)N * 128, 256);
    unsigned short* agg2 = (unsigned short*)(ws + off); off = alignUp(off + (size_t)N * 128 * 2, 256);
    float*          pooled = (float*)(ws + off); off = alignUp(off + (size_t)G * 128 * 4, 256);
    (void)ws_size;

    unsigned short* Wl1b = wbuf;
    unsigned short* Wr1b = wbuf + 8192;
    unsigned short* Wl2b = wbuf + 16384;
    unsigned short* Wr2b = wbuf + 32768;

    // phase A: LDS bucket histogram + cvt_x + cvt_w + zero(pooled) + graph bounds
    k_phase_a<<<bHist + bCvtX + bCvtW + bZero + 1, 256, 0, stream>>>(
        dst, bhist, E,
        x, xb, xf8, N * 64,
        Wl1, Wr1, Wl2, Wr2, wbuf,
        pooled,
        batch, gstart, N, G,
        bHist, bCvtX, bCvtW, bZero);

    // bucket scans + bucket-grouped scatter + per-bucket counting sort
    k_scan_bh<<<256, 256, 0, stream>>>(bhist, btot, bHist);
    k_scatter_b<<<bHist, 256, 0, stream>>>(src, dst, bhist, btot, ebuf, E);
    k_bucket_csr<<<NB, 256, 0, stream>>>(ebuf, btot, row_start, csr_src, N, NB);

    // layer 1: gather (fp8) -> MFMA linear (emits h1 bf16 + h1f8 fp8)
    k_gather1<<<(N + 31) / 32, 256, 0, stream>>>(xf8, row_start, csr_src, agg1, N);
    k_linear_mfma<64, false><<<(N + 127) / 128, 256, 0, stream>>>(
        agg1, xb, Wl1b, bl1, Wr1b, h1, h1f8, nullptr, nullptr, N);

    // layer 2: gather -> MFMA linear + per-graph pool (fp32 atomics)
    k_gather2<<<(N + 15) / 16, 256, 0, stream>>>(h1f8, row_start, csr_src, agg2, N);
    k_linear_mfma<128, true><<<(N + 127) / 128, 256, 0, stream>>>(
        agg2, h1, Wl2b, bl2, Wr2b, nullptr, nullptr, batch, pooled, N);

    // tiny head: mean + 128->2 linear + log_softmax
    k_head<<<G, 64, 0, stream>>>(pooled, gstart, Wout, bout, out);
}